// Round 3
// baseline (1969.564 us; speedup 1.0000x reference)
//
#include <hip/hip_runtime.h>

#define BN_EPS 1e-5f

// ---------------- graph preprocessing (CSR by dst) ----------------

__global__ void zero_graph_k(int* __restrict__ cnt, float* __restrict__ degf, int n) {
  int i = blockIdx.x * blockDim.x + threadIdx.x;
  if (i < n) { cnt[i] = 0; degf[i] = 0.f; }
}

__global__ void hist_k(const int* __restrict__ dst, const float* __restrict__ w,
                       int* __restrict__ cnt, float* __restrict__ degf, int e) {
  int i = blockIdx.x * blockDim.x + threadIdx.x;
  if (i < e) {
    int d = dst[i];
    atomicAdd(&cnt[d], 1);
    unsafeAtomicAdd(&degf[d], w[i]);
  }
}

__global__ void dinv_k(float* __restrict__ degf, int n) {
  int i = blockIdx.x * blockDim.x + threadIdx.x;
  if (i < n) degf[i] = rsqrtf(1.0f + degf[i]);  // self-loop weight 1 included
}

// single-block scan: cnt -> rowptr; cursor (aliased onto cnt) = rowptr copy
__global__ void scan_k(int* __restrict__ cnt, int* __restrict__ rowptr, int n) {
  const int T = 1024;
  __shared__ int part[T];
  int t = threadIdx.x;
  int chunk = (n + T - 1) / T;
  int beg = t * chunk, end = min(beg + chunk, n);
  int s = 0;
  for (int i = beg; i < end; ++i) s += cnt[i];
  part[t] = s;
  __syncthreads();
  for (int off = 1; off < T; off <<= 1) {
    int v = (t >= off) ? part[t - off] : 0;
    __syncthreads();
    part[t] += v;
    __syncthreads();
  }
  int base = part[t] - s;
  for (int i = beg; i < end; ++i) {
    int c = cnt[i];
    rowptr[i] = base;
    cnt[i] = base;
    base += c;
  }
  if (t == T - 1) rowptr[n] = part[T - 1];
}

__global__ void scatter_k(const int* __restrict__ src, const int* __restrict__ dst,
                          const float* __restrict__ w, const float* __restrict__ dinv,
                          int* __restrict__ cursor, int* __restrict__ csr_src,
                          float* __restrict__ csr_coef, int e) {
  int i = blockIdx.x * blockDim.x + threadIdx.x;
  if (i < e) {
    int d = dst[i];
    int s = src[i];
    int pos = atomicAdd(&cursor[d], 1);
    csr_src[pos] = s;
    csr_coef[pos] = dinv[s] * w[i] * dinv[d];
  }
}

// ---------------- GEMM: out[r][jb*JT : (jb+1)*JT] = f(H[row]) @ W[:, jtile] ----
// f = identity, or fused BN-apply + ReLU of the previous layer (BNIN).
// JT-wide column tile keeps LDS small -> high occupancy.

template <int FIN, int FOUT, int JT, int ROWS, bool BNIN>
__global__ void gemm_k(const float* __restrict__ H, const int* __restrict__ xidx,
                       const float* __restrict__ scale, const float* __restrict__ shift,
                       const float* __restrict__ W, float* __restrict__ out, int n) {
  __shared__ __align__(16) float Ws[FIN * JT];
  __shared__ float scs[BNIN ? FIN : 1], shs[BNIN ? FIN : 1];
  const int jb = blockIdx.y;
  for (int i = threadIdx.x; i < FIN * JT; i += blockDim.x) {
    int k = i / JT, j = i % JT;
    Ws[i] = W[k * FOUT + jb * JT + j];
  }
  if (BNIN) {
    for (int i = threadIdx.x; i < FIN; i += blockDim.x) { scs[i] = scale[i]; shs[i] = shift[i]; }
  }
  __syncthreads();

  constexpr int TPR = JT / 4;
  const int lane_j = threadIdx.x % TPR;
  const int rpi = blockDim.x / TPR;
  const int r0 = blockIdx.x * ROWS;
  const int rend = min(r0 + ROWS, n);

  for (int r = r0 + threadIdx.x / TPR; r < rend; r += rpi) {
    const int row = xidx ? xidx[r] : r;
    const float4* h4 = (const float4*)(H + (size_t)row * FIN);
    float4 acc = make_float4(0.f, 0.f, 0.f, 0.f);
#pragma unroll
    for (int k4 = 0; k4 < FIN / 4; ++k4) {
      float4 h = h4[k4];
      if (BNIN) {
        h.x = fmaxf(h.x * scs[k4 * 4 + 0] + shs[k4 * 4 + 0], 0.f);
        h.y = fmaxf(h.y * scs[k4 * 4 + 1] + shs[k4 * 4 + 1], 0.f);
        h.z = fmaxf(h.z * scs[k4 * 4 + 2] + shs[k4 * 4 + 2], 0.f);
        h.w = fmaxf(h.w * scs[k4 * 4 + 3] + shs[k4 * 4 + 3], 0.f);
      }
      const float* wb = &Ws[(k4 * 4) * JT + lane_j * 4];
      const float4 w0 = *(const float4*)(wb);
      const float4 w1 = *(const float4*)(wb + JT);
      const float4 w2 = *(const float4*)(wb + 2 * JT);
      const float4 w3 = *(const float4*)(wb + 3 * JT);
      acc.x += h.x * w0.x + h.y * w1.x + h.z * w2.x + h.w * w3.x;
      acc.y += h.x * w0.y + h.y * w1.y + h.z * w2.y + h.w * w3.y;
      acc.z += h.x * w0.z + h.y * w1.z + h.z * w2.z + h.w * w3.z;
      acc.w += h.x * w0.w + h.y * w1.w + h.z * w2.w + h.w * w3.w;
    }
    *(float4*)(out + (size_t)r * FOUT + jb * JT + lane_j * 4) = acc;
  }
}

// ---------------- CSR aggregation (gather-only, no atomics) ----------------
// agg[r] = hW[r]*dinv[r]^2 + b + sum_{e in row r} hW[csr_src[e]] * csr_coef[e]
// 8 floats per thread; 2-edge unrolled gather loop.

template <int FOUT>
__global__ void agg_csr_k(const float* __restrict__ hW, const int* __restrict__ rowptr,
                          const int* __restrict__ csr_src, const float* __restrict__ csr_coef,
                          const float* __restrict__ dinv, const float* __restrict__ b,
                          float* __restrict__ agg, int n) {
  constexpr int TPR = FOUT / 8;
  int gid = blockIdx.x * blockDim.x + threadIdx.x;
  int row = gid / TPR, j = gid % TPR;
  if (row >= n) return;

  const float di = dinv[row];
  const float c0 = di * di;
  const float* hrow = hW + (size_t)row * FOUT + j * 8;
  const float4 h0 = *(const float4*)(hrow);
  const float4 h1 = *(const float4*)(hrow + 4);
  const float4 bb0 = *(const float4*)(b + j * 8);
  const float4 bb1 = *(const float4*)(b + j * 8 + 4);
  float4 a0 = make_float4(h0.x * c0 + bb0.x, h0.y * c0 + bb0.y, h0.z * c0 + bb0.z, h0.w * c0 + bb0.w);
  float4 a1 = make_float4(h1.x * c0 + bb1.x, h1.y * c0 + bb1.y, h1.z * c0 + bb1.z, h1.w * c0 + bb1.w);

  const int e0 = rowptr[row], e1 = rowptr[row + 1];
  int ee = e0;
  for (; ee + 1 < e1; ee += 2) {
    const int s0 = csr_src[ee], s1 = csr_src[ee + 1];
    const float cc0 = csr_coef[ee], cc1 = csr_coef[ee + 1];
    const float* p0 = hW + (size_t)s0 * FOUT + j * 8;
    const float* p1 = hW + (size_t)s1 * FOUT + j * 8;
    const float4 v00 = *(const float4*)(p0);
    const float4 v01 = *(const float4*)(p0 + 4);
    const float4 v10 = *(const float4*)(p1);
    const float4 v11 = *(const float4*)(p1 + 4);
    a0.x += v00.x * cc0; a0.y += v00.y * cc0; a0.z += v00.z * cc0; a0.w += v00.w * cc0;
    a1.x += v01.x * cc0; a1.y += v01.y * cc0; a1.z += v01.z * cc0; a1.w += v01.w * cc0;
    a0.x += v10.x * cc1; a0.y += v10.y * cc1; a0.z += v10.z * cc1; a0.w += v10.w * cc1;
    a1.x += v11.x * cc1; a1.y += v11.y * cc1; a1.z += v11.z * cc1; a1.w += v11.w * cc1;
  }
  if (ee < e1) {
    const int s0 = csr_src[ee];
    const float cc0 = csr_coef[ee];
    const float* p0 = hW + (size_t)s0 * FOUT + j * 8;
    const float4 v00 = *(const float4*)(p0);
    const float4 v01 = *(const float4*)(p0 + 4);
    a0.x += v00.x * cc0; a0.y += v00.y * cc0; a0.z += v00.z * cc0; a0.w += v00.w * cc0;
    a1.x += v01.x * cc0; a1.y += v01.y * cc0; a1.z += v01.z * cc0; a1.w += v01.w * cc0;
  }

  float* orow = agg + (size_t)row * FOUT + j * 8;
  *(float4*)(orow) = a0;
  *(float4*)(orow + 4) = a1;
}

// ---------------- batch norm ----------------

__global__ void zero_k(float* __restrict__ p, int cnt) {
  int i = blockIdx.x * blockDim.x + threadIdx.x;
  if (i < cnt) p[i] = 0.f;
}

template <int FOUT>
__global__ void bn_stats_k(const float* __restrict__ h, float* __restrict__ gsum,
                           float* __restrict__ gsq, int n) {
  constexpr int COPIES = 256 / FOUT;
  __shared__ float ls[256];
  __shared__ float lq[256];
  const int col = threadIdx.x % FOUT;
  const int cp = threadIdx.x / FOUT;
  float s = 0.f, q = 0.f;
  for (int r = blockIdx.x * COPIES + cp; r < n; r += gridDim.x * COPIES) {
    float v = h[(size_t)r * FOUT + col];
    s += v;
    q += v * v;
  }
  ls[threadIdx.x] = s;
  lq[threadIdx.x] = q;
  __syncthreads();
  if (threadIdx.x < FOUT) {
    float ts = 0.f, tq = 0.f;
#pragma unroll
    for (int c = 0; c < COPIES; ++c) {
      ts += ls[c * FOUT + col];
      tq += lq[c * FOUT + col];
    }
    unsafeAtomicAdd(&gsum[col], ts);
    unsafeAtomicAdd(&gsq[col], tq);
  }
}

template <int FOUT>
__global__ void bn_finalize_k(const float* __restrict__ gsum, const float* __restrict__ gsq,
                              const float* __restrict__ g, const float* __restrict__ be,
                              float* __restrict__ scale, float* __restrict__ shift, int n) {
  int c = threadIdx.x;
  if (c >= FOUT) return;
  float inv_n = 1.0f / (float)n;
  float mu = gsum[c] * inv_n;
  float var = gsq[c] * inv_n - mu * mu;
  float sc = g[c] * rsqrtf(var + BN_EPS);
  scale[c] = sc;
  shift[c] = be[c] - mu * sc;
}

template <int FOUT, bool RELU>
__global__ void bn_apply_k(const float* __restrict__ in, const float* __restrict__ scale,
                           const float* __restrict__ shift, float* __restrict__ out, int n) {
  constexpr int TPR = FOUT / 4;
  int gid = blockIdx.x * blockDim.x + threadIdx.x;
  int row = gid / TPR, j = gid % TPR;
  if (row >= n) return;
  float4 v = *(const float4*)(in + (size_t)row * FOUT + j * 4);
  float4 sc = *(const float4*)(scale + j * 4);
  float4 sh = *(const float4*)(shift + j * 4);
  float4 o;
  o.x = v.x * sc.x + sh.x;
  o.y = v.y * sc.y + sh.y;
  o.z = v.z * sc.z + sh.z;
  o.w = v.w * sc.w + sh.w;
  if (RELU) {
    o.x = fmaxf(o.x, 0.f);
    o.y = fmaxf(o.y, 0.f);
    o.z = fmaxf(o.z, 0.f);
    o.w = fmaxf(o.w, 0.f);
  }
  *(float4*)(out + (size_t)row * FOUT + j * 4) = o;
}

// ---------------- launch ----------------

extern "C" void kernel_launch(void* const* d_in, const int* in_sizes, int n_in,
                              void* d_out, int out_size, void* d_ws, size_t ws_size,
                              hipStream_t stream) {
  const int* x = (const int*)d_in[0];
  const int* ei = (const int*)d_in[1];
  const float* w = (const float*)d_in[2];
  const float* emb = (const float*)d_in[3];
  const float* W1 = (const float*)d_in[4];
  const float* b1 = (const float*)d_in[5];
  const float* g1 = (const float*)d_in[6];
  const float* be1 = (const float*)d_in[7];
  const float* W2 = (const float*)d_in[8];
  const float* b2 = (const float*)d_in[9];
  const float* g2 = (const float*)d_in[10];
  const float* be2 = (const float*)d_in[11];
  const float* W3 = (const float*)d_in[12];
  const float* b3 = (const float*)d_in[13];
  const float* g3 = (const float*)d_in[14];
  const float* be3 = (const float*)d_in[15];

  const int n = in_sizes[0];
  const int e = in_sizes[2];
  const int* src = ei;
  const int* dst = ei + e;

  float* ws = (float*)d_ws;
  float* bufA = ws;                              // n*128 (hW)
  float* bufB = bufA + (size_t)n * 128;          // n*128 (agg)
  float* dinv = bufB + (size_t)n * 128;          // n
  int* rowptr = (int*)(dinv + n);                // n+1
  int* cursor = rowptr + (n + 1);                // n (doubles as cnt)
  int* csr_src = cursor + n;                     // e
  float* csr_coef = (float*)(csr_src + e);       // e
  float* gsum = csr_coef + e;                    // 128
  float* gsq = gsum + 128;                       // 128
  float* scale = gsq + 128;                      // 128
  float* shift = scale + 128;                    // 128

  const int B = 256;
  dim3 blk(B);

  // CSR build (shared by all layers)
  zero_graph_k<<<(n + B - 1) / B, blk, 0, stream>>>(cursor, dinv, n);
  hist_k<<<(e + B - 1) / B, blk, 0, stream>>>(dst, w, cursor, dinv, e);
  dinv_k<<<(n + B - 1) / B, blk, 0, stream>>>(dinv, n);
  scan_k<<<1, 1024, 0, stream>>>(cursor, rowptr, n);
  scatter_k<<<(e + B - 1) / B, blk, 0, stream>>>(src, dst, w, dinv, cursor, csr_src, csr_coef, e);

  const int ROWS = 128;
  const int gx = (n + ROWS - 1) / ROWS;

  // ---- layer 1: gemm(emb[x]) -> bufA; agg -> bufB; stats
  gemm_k<128, 128, 64, ROWS, false><<<dim3(gx, 2), blk, 0, stream>>>(emb, x, nullptr, nullptr, W1, bufA, n);
  agg_csr_k<128><<<((size_t)n * 16 + B - 1) / B, blk, 0, stream>>>(bufA, rowptr, csr_src, csr_coef, dinv, b1, bufB, n);
  zero_k<<<1, blk, 0, stream>>>(gsum, 256);
  bn_stats_k<128><<<256, blk, 0, stream>>>(bufB, gsum, gsq, n);
  bn_finalize_k<128><<<1, 128, 0, stream>>>(gsum, gsq, g1, be1, scale, shift, n);

  // ---- layer 2: gemm(BN+ReLU(bufB)) -> bufA; agg -> bufB; stats
  gemm_k<128, 64, 32, ROWS, true><<<dim3(gx, 2), blk, 0, stream>>>(bufB, nullptr, scale, shift, W2, bufA, n);
  agg_csr_k<64><<<((size_t)n * 8 + B - 1) / B, blk, 0, stream>>>(bufA, rowptr, csr_src, csr_coef, dinv, b2, bufB, n);
  zero_k<<<1, blk, 0, stream>>>(gsum, 256);
  bn_stats_k<64><<<256, blk, 0, stream>>>(bufB, gsum, gsq, n);
  bn_finalize_k<64><<<1, 64, 0, stream>>>(gsum, gsq, g2, be2, scale, shift, n);

  // ---- layer 3: gemm(BN+ReLU(bufB)) -> bufA; agg -> bufB; BN -> d_out
  gemm_k<64, 32, 32, ROWS, true><<<dim3(gx, 1), blk, 0, stream>>>(bufB, nullptr, scale, shift, W3, bufA, n);
  agg_csr_k<32><<<((size_t)n * 4 + B - 1) / B, blk, 0, stream>>>(bufA, rowptr, csr_src, csr_coef, dinv, b3, bufB, n);
  zero_k<<<1, blk, 0, stream>>>(gsum, 256);
  bn_stats_k<32><<<256, blk, 0, stream>>>(bufB, gsum, gsq, n);
  bn_finalize_k<32><<<1, 32, 0, stream>>>(gsum, gsq, g3, be3, scale, shift, n);
  bn_apply_k<32, false><<<((size_t)n * 8 + B - 1) / B, blk, 0, stream>>>(bufB, scale, shift, (float*)d_out, n);
}

// Round 4
// 515.888 us; speedup vs baseline: 3.8178x; 3.8178x over previous
//
#include <hip/hip_runtime.h>

#define BN_EPS 1e-5f

// ---------------- graph preprocessing (CSR by dst) ----------------

__global__ void zero_graph_k(int* __restrict__ cnt, float* __restrict__ degf, int n) {
  int i = blockIdx.x * blockDim.x + threadIdx.x;
  if (i < n) { cnt[i] = 0; degf[i] = 0.f; }
}

__global__ void hist_k(const int* __restrict__ dst, const float* __restrict__ w,
                       int* __restrict__ cnt, float* __restrict__ degf, int e) {
  int i = blockIdx.x * blockDim.x + threadIdx.x;
  if (i < e) {
    int d = dst[i];
    atomicAdd(&cnt[d], 1);
    unsafeAtomicAdd(&degf[d], w[i]);
  }
}

__global__ void dinv_k(float* __restrict__ degf, int n) {
  int i = blockIdx.x * blockDim.x + threadIdx.x;
  if (i < n) degf[i] = rsqrtf(1.0f + degf[i]);  // self-loop weight 1 included
}

// single-block scan: cnt -> rowptr; cursor (aliased onto cnt) = rowptr copy
__global__ void scan_k(int* __restrict__ cnt, int* __restrict__ rowptr, int n) {
  const int T = 1024;
  __shared__ int part[T];
  int t = threadIdx.x;
  int chunk = (n + T - 1) / T;
  int beg = t * chunk, end = min(beg + chunk, n);
  int s = 0;
  for (int i = beg; i < end; ++i) s += cnt[i];
  part[t] = s;
  __syncthreads();
  for (int off = 1; off < T; off <<= 1) {
    int v = (t >= off) ? part[t - off] : 0;
    __syncthreads();
    part[t] += v;
    __syncthreads();
  }
  int base = part[t] - s;
  for (int i = beg; i < end; ++i) {
    int c = cnt[i];
    rowptr[i] = base;
    cnt[i] = base;
    base += c;
  }
  if (t == T - 1) rowptr[n] = part[T - 1];
}

__global__ void scatter_k(const int* __restrict__ src, const int* __restrict__ dst,
                          const float* __restrict__ w, const float* __restrict__ dinv,
                          int* __restrict__ cursor, int* __restrict__ csr_src,
                          float* __restrict__ csr_coef, int e) {
  int i = blockIdx.x * blockDim.x + threadIdx.x;
  if (i < e) {
    int d = dst[i];
    int s = src[i];
    int pos = atomicAdd(&cursor[d], 1);
    csr_src[pos] = s;
    csr_coef[pos] = dinv[s] * w[i] * dinv[d];
  }
}

// ---------------- block-tiled GEMM with LDS staging ----------------
// out[r0..r0+RT)[jb*JT..] = f(H[row]) @ W[:, jtile]
// f = identity or fused BN-apply+ReLU (BNIN). GATHER: row = xidx[r].
// H-tile staged to LDS once (coalesced, each byte read once), W-tile per jb.
// H granules XOR-swizzled by (row>>2)&7 to avoid stride-512B bank conflicts.

template <int FIN, int FOUT, int JT, int JTILES, int RPG, bool BNIN, bool GATHER>
__global__ __launch_bounds__(256) void gemm_tile_k(
    const float* __restrict__ H, const int* __restrict__ xidx,
    const float* __restrict__ scale, const float* __restrict__ shift,
    const float* __restrict__ W, float* __restrict__ out, int n) {
  constexpr int TPC = JT / 4;          // threads per row-slice (cols)
  constexpr int G = 256 / TPC;         // row groups per block
  constexpr int RT = G * RPG;          // rows per block
  constexpr int C4 = FIN / 4;          // float4 granules per H row

  __shared__ float4 Ht[RT * C4];
  __shared__ float4 Wsf[FIN * JT / 4];

  const int r0 = blockIdx.x * RT;
  const int t = threadIdx.x;

  // ---- stage H tile (fully coalesced; BN+ReLU fused here if BNIN)
  constexpr int NH = RT * C4 / 256;
#pragma unroll
  for (int i = 0; i < NH; ++i) {
    int idx = t + 256 * i;
    int r = idx / C4, c4 = idx % C4;
    int gr = r0 + r;
    if (gr < n) {
      int srow = GATHER ? xidx[gr] : gr;
      float4 v = *(const float4*)(H + (size_t)srow * FIN + c4 * 4);
      if (BNIN) {
        float4 sc = *(const float4*)(scale + c4 * 4);
        float4 sh = *(const float4*)(shift + c4 * 4);
        v.x = fmaxf(v.x * sc.x + sh.x, 0.f);
        v.y = fmaxf(v.y * sc.y + sh.y, 0.f);
        v.z = fmaxf(v.z * sc.z + sh.z, 0.f);
        v.w = fmaxf(v.w * sc.w + sh.w, 0.f);
      }
      Ht[r * C4 + (c4 ^ ((r >> 2) & 7))] = v;
    }
  }

  const int g = t / TPC;
  const int lj = t % TPC;
  const int rbase = g * RPG;

  for (int jb = 0; jb < JTILES; ++jb) {
    // ---- stage W tile
    constexpr int NW = FIN * JT / 4 / 256;
#pragma unroll
    for (int i = 0; i < NW; ++i) {
      int idx = t + 256 * i;
      int k = idx / TPC, jg = idx % TPC;
      Wsf[idx] = *(const float4*)(W + (size_t)k * FOUT + jb * JT + jg * 4);
    }
    __syncthreads();

    // ---- compute: RPG rows x 4 cols per thread
    float4 acc[RPG];
#pragma unroll
    for (int rr = 0; rr < RPG; ++rr) acc[rr] = make_float4(0.f, 0.f, 0.f, 0.f);

    for (int k4 = 0; k4 < C4; ++k4) {
      float4 wv0 = Wsf[(k4 * 4 + 0) * TPC + lj];
      float4 wv1 = Wsf[(k4 * 4 + 1) * TPC + lj];
      float4 wv2 = Wsf[(k4 * 4 + 2) * TPC + lj];
      float4 wv3 = Wsf[(k4 * 4 + 3) * TPC + lj];
#pragma unroll
      for (int rr = 0; rr < RPG; ++rr) {
        int r = rbase + rr;
        float4 h = Ht[r * C4 + (k4 ^ ((r >> 2) & 7))];
        acc[rr].x += h.x * wv0.x + h.y * wv1.x + h.z * wv2.x + h.w * wv3.x;
        acc[rr].y += h.x * wv0.y + h.y * wv1.y + h.z * wv2.y + h.w * wv3.y;
        acc[rr].z += h.x * wv0.z + h.y * wv1.z + h.z * wv2.z + h.w * wv3.z;
        acc[rr].w += h.x * wv0.w + h.y * wv1.w + h.z * wv2.w + h.w * wv3.w;
      }
    }

    // ---- write out
#pragma unroll
    for (int rr = 0; rr < RPG; ++rr) {
      int gr = r0 + rbase + rr;
      if (gr < n)
        *(float4*)(out + (size_t)gr * FOUT + jb * JT + lj * 4) = acc[rr];
    }
    if (jb + 1 < JTILES) __syncthreads();  // before overwriting Wsf
  }
}

// ---------------- CSR aggregation (gather-only, no atomics) ----------------

template <int FOUT>
__global__ void agg_csr_k(const float* __restrict__ hW, const int* __restrict__ rowptr,
                          const int* __restrict__ csr_src, const float* __restrict__ csr_coef,
                          const float* __restrict__ dinv, const float* __restrict__ b,
                          float* __restrict__ agg, int n) {
  constexpr int TPR = FOUT / 8;
  int gid = blockIdx.x * blockDim.x + threadIdx.x;
  int row = gid / TPR, j = gid % TPR;
  if (row >= n) return;

  const float di = dinv[row];
  const float c0 = di * di;
  const float* hrow = hW + (size_t)row * FOUT + j * 8;
  const float4 h0 = *(const float4*)(hrow);
  const float4 h1 = *(const float4*)(hrow + 4);
  const float4 bb0 = *(const float4*)(b + j * 8);
  const float4 bb1 = *(const float4*)(b + j * 8 + 4);
  float4 a0 = make_float4(h0.x * c0 + bb0.x, h0.y * c0 + bb0.y, h0.z * c0 + bb0.z, h0.w * c0 + bb0.w);
  float4 a1 = make_float4(h1.x * c0 + bb1.x, h1.y * c0 + bb1.y, h1.z * c0 + bb1.z, h1.w * c0 + bb1.w);

  const int e0 = rowptr[row], e1 = rowptr[row + 1];
  int ee = e0;
  for (; ee + 1 < e1; ee += 2) {
    const int s0 = csr_src[ee], s1 = csr_src[ee + 1];
    const float cc0 = csr_coef[ee], cc1 = csr_coef[ee + 1];
    const float* p0 = hW + (size_t)s0 * FOUT + j * 8;
    const float* p1 = hW + (size_t)s1 * FOUT + j * 8;
    const float4 v00 = *(const float4*)(p0);
    const float4 v01 = *(const float4*)(p0 + 4);
    const float4 v10 = *(const float4*)(p1);
    const float4 v11 = *(const float4*)(p1 + 4);
    a0.x += v00.x * cc0; a0.y += v00.y * cc0; a0.z += v00.z * cc0; a0.w += v00.w * cc0;
    a1.x += v01.x * cc0; a1.y += v01.y * cc0; a1.z += v01.z * cc0; a1.w += v01.w * cc0;
    a0.x += v10.x * cc1; a0.y += v10.y * cc1; a0.z += v10.z * cc1; a0.w += v10.w * cc1;
    a1.x += v11.x * cc1; a1.y += v11.y * cc1; a1.z += v11.z * cc1; a1.w += v11.w * cc1;
  }
  if (ee < e1) {
    const int s0 = csr_src[ee];
    const float cc0 = csr_coef[ee];
    const float* p0 = hW + (size_t)s0 * FOUT + j * 8;
    const float4 v00 = *(const float4*)(p0);
    const float4 v01 = *(const float4*)(p0 + 4);
    a0.x += v00.x * cc0; a0.y += v00.y * cc0; a0.z += v00.z * cc0; a0.w += v00.w * cc0;
    a1.x += v01.x * cc0; a1.y += v01.y * cc0; a1.z += v01.z * cc0; a1.w += v01.w * cc0;
  }

  float* orow = agg + (size_t)row * FOUT + j * 8;
  *(float4*)(orow) = a0;
  *(float4*)(orow + 4) = a1;
}

// ---------------- batch norm ----------------

__global__ void zero_k(float* __restrict__ p, int cnt) {
  int i = blockIdx.x * blockDim.x + threadIdx.x;
  if (i < cnt) p[i] = 0.f;
}

template <int FOUT>
__global__ void bn_stats_k(const float* __restrict__ h, float* __restrict__ gsum,
                           float* __restrict__ gsq, int n) {
  constexpr int COPIES = 256 / FOUT;
  __shared__ float ls[256];
  __shared__ float lq[256];
  const int col = threadIdx.x % FOUT;
  const int cp = threadIdx.x / FOUT;
  float s = 0.f, q = 0.f;
  for (int r = blockIdx.x * COPIES + cp; r < n; r += gridDim.x * COPIES) {
    float v = h[(size_t)r * FOUT + col];
    s += v;
    q += v * v;
  }
  ls[threadIdx.x] = s;
  lq[threadIdx.x] = q;
  __syncthreads();
  if (threadIdx.x < FOUT) {
    float ts = 0.f, tq = 0.f;
#pragma unroll
    for (int c = 0; c < COPIES; ++c) {
      ts += ls[c * FOUT + col];
      tq += lq[c * FOUT + col];
    }
    unsafeAtomicAdd(&gsum[col], ts);
    unsafeAtomicAdd(&gsq[col], tq);
  }
}

template <int FOUT>
__global__ void bn_finalize_k(const float* __restrict__ gsum, const float* __restrict__ gsq,
                              const float* __restrict__ g, const float* __restrict__ be,
                              float* __restrict__ scale, float* __restrict__ shift, int n) {
  int c = threadIdx.x;
  if (c >= FOUT) return;
  float inv_n = 1.0f / (float)n;
  float mu = gsum[c] * inv_n;
  float var = gsq[c] * inv_n - mu * mu;
  float sc = g[c] * rsqrtf(var + BN_EPS);
  scale[c] = sc;
  shift[c] = be[c] - mu * sc;
}

template <int FOUT, bool RELU>
__global__ void bn_apply_k(const float* __restrict__ in, const float* __restrict__ scale,
                           const float* __restrict__ shift, float* __restrict__ out, int n) {
  constexpr int TPR = FOUT / 4;
  int gid = blockIdx.x * blockDim.x + threadIdx.x;
  int row = gid / TPR, j = gid % TPR;
  if (row >= n) return;
  float4 v = *(const float4*)(in + (size_t)row * FOUT + j * 4);
  float4 sc = *(const float4*)(scale + j * 4);
  float4 sh = *(const float4*)(shift + j * 4);
  float4 o;
  o.x = v.x * sc.x + sh.x;
  o.y = v.y * sc.y + sh.y;
  o.z = v.z * sc.z + sh.z;
  o.w = v.w * sc.w + sh.w;
  if (RELU) {
    o.x = fmaxf(o.x, 0.f);
    o.y = fmaxf(o.y, 0.f);
    o.z = fmaxf(o.z, 0.f);
    o.w = fmaxf(o.w, 0.f);
  }
  *(float4*)(out + (size_t)row * FOUT + j * 4) = o;
}

// ---------------- launch ----------------

static inline size_t pad4(size_t v) { return (v + 3) & ~(size_t)3; }

extern "C" void kernel_launch(void* const* d_in, const int* in_sizes, int n_in,
                              void* d_out, int out_size, void* d_ws, size_t ws_size,
                              hipStream_t stream) {
  const int* x = (const int*)d_in[0];
  const int* ei = (const int*)d_in[1];
  const float* w = (const float*)d_in[2];
  const float* emb = (const float*)d_in[3];
  const float* W1 = (const float*)d_in[4];
  const float* b1 = (const float*)d_in[5];
  const float* g1 = (const float*)d_in[6];
  const float* be1 = (const float*)d_in[7];
  const float* W2 = (const float*)d_in[8];
  const float* b2 = (const float*)d_in[9];
  const float* g2 = (const float*)d_in[10];
  const float* be2 = (const float*)d_in[11];
  const float* W3 = (const float*)d_in[12];
  const float* b3 = (const float*)d_in[13];
  const float* g3 = (const float*)d_in[14];
  const float* be3 = (const float*)d_in[15];

  const int n = in_sizes[0];
  const int e = in_sizes[2];
  const int* src = ei;
  const int* dst = ei + e;

  // 16B-aligned workspace carve-up
  float* ws = (float*)d_ws;
  size_t off = 0;
  float* bufA = ws + off; off += pad4((size_t)n * 128);
  float* bufB = ws + off; off += pad4((size_t)n * 128);
  float* dinv = ws + off; off += pad4(n);
  int* rowptr = (int*)(ws + off); off += pad4(n + 1);
  int* cursor = (int*)(ws + off); off += pad4(n);
  int* csr_src = (int*)(ws + off); off += pad4(e);
  float* csr_coef = ws + off; off += pad4(e);
  float* gsum = ws + off; off += 128;
  float* gsq = ws + off; off += 128;
  float* scale = ws + off; off += 128;
  float* shift = ws + off; off += 128;

  const int B = 256;
  dim3 blk(B);

  // CSR build (shared by all layers)
  zero_graph_k<<<(n + B - 1) / B, blk, 0, stream>>>(cursor, dinv, n);
  hist_k<<<(e + B - 1) / B, blk, 0, stream>>>(dst, w, cursor, dinv, e);
  dinv_k<<<(n + B - 1) / B, blk, 0, stream>>>(dinv, n);
  scan_k<<<1, 1024, 0, stream>>>(cursor, rowptr, n);
  scatter_k<<<(e + B - 1) / B, blk, 0, stream>>>(src, dst, w, dinv, cursor, csr_src, csr_coef, e);

  const int gx = (n + 63) / 64;  // RT = 64 for all layers

  // ---- layer 1: gemm(emb[x]) -> bufA; agg -> bufB; stats
  gemm_tile_k<128, 128, 64, 2, 4, false, true><<<gx, blk, 0, stream>>>(emb, x, nullptr, nullptr, W1, bufA, n);
  agg_csr_k<128><<<((size_t)n * 16 + B - 1) / B, blk, 0, stream>>>(bufA, rowptr, csr_src, csr_coef, dinv, b1, bufB, n);
  zero_k<<<1, blk, 0, stream>>>(gsum, 256);
  bn_stats_k<128><<<256, blk, 0, stream>>>(bufB, gsum, gsq, n);
  bn_finalize_k<128><<<1, 128, 0, stream>>>(gsum, gsq, g1, be1, scale, shift, n);

  // ---- layer 2: gemm(BN+ReLU(bufB)) -> bufA; agg -> bufB; stats
  gemm_tile_k<128, 64, 64, 1, 4, true, false><<<gx, blk, 0, stream>>>(bufB, nullptr, scale, shift, W2, bufA, n);
  agg_csr_k<64><<<((size_t)n * 8 + B - 1) / B, blk, 0, stream>>>(bufA, rowptr, csr_src, csr_coef, dinv, b2, bufB, n);
  zero_k<<<1, blk, 0, stream>>>(gsum, 256);
  bn_stats_k<64><<<256, blk, 0, stream>>>(bufB, gsum, gsq, n);
  bn_finalize_k<64><<<1, 64, 0, stream>>>(gsum, gsq, g2, be2, scale, shift, n);

  // ---- layer 3: gemm(BN+ReLU(bufB)) -> bufA; agg -> bufB; BN -> d_out
  gemm_tile_k<64, 32, 32, 1, 2, true, false><<<gx, blk, 0, stream>>>(bufB, nullptr, scale, shift, W3, bufA, n);
  agg_csr_k<32><<<((size_t)n * 4 + B - 1) / B, blk, 0, stream>>>(bufA, rowptr, csr_src, csr_coef, dinv, b3, bufB, n);
  zero_k<<<1, blk, 0, stream>>>(gsum, 256);
  bn_stats_k<32><<<256, blk, 0, stream>>>(bufB, gsum, gsq, n);
  bn_finalize_k<32><<<1, 32, 0, stream>>>(gsum, gsq, g3, be3, scale, shift, n);
  bn_apply_k<32, false><<<((size_t)n * 8 + B - 1) / B, blk, 0, stream>>>(bufB, scale, shift, (float*)d_out, n);
}

// Round 5
// 412.389 us; speedup vs baseline: 4.7760x; 1.2510x over previous
//
#include <hip/hip_runtime.h>

#define BN_EPS 1e-5f

// ---------------- graph preprocessing (CSR by dst) ----------------

__global__ void zero_graph_k(int* __restrict__ cnt, float* __restrict__ degf,
                             float* __restrict__ gstats, int n) {
  int i = blockIdx.x * blockDim.x + threadIdx.x;
  if (i < n) { cnt[i] = 0; degf[i] = 0.f; }
  if (i < 256) gstats[i] = 0.f;  // gsum[128] + gsq[128]
}

__global__ void hist_k(const int* __restrict__ dst, const float* __restrict__ w,
                       int* __restrict__ cnt, float* __restrict__ degf, int e) {
  int i = blockIdx.x * blockDim.x + threadIdx.x;
  if (i < e) {
    int d = dst[i];
    atomicAdd(&cnt[d], 1);
    unsafeAtomicAdd(&degf[d], w[i]);
  }
}

__global__ void dinv_k(float* __restrict__ degf, int n) {
  int i = blockIdx.x * blockDim.x + threadIdx.x;
  if (i < n) degf[i] = rsqrtf(1.0f + degf[i]);  // self-loop weight 1 included
}

// ---- 3-phase multi-block exclusive scan of cnt -> rowptr (+cursor copy) ----

__global__ void scan_partial_k(const int* __restrict__ cnt, int* __restrict__ bsum, int n) {
  __shared__ int s[256];
  int idx = blockIdx.x * 256 + threadIdx.x;
  s[threadIdx.x] = (idx < n) ? cnt[idx] : 0;
  __syncthreads();
  for (int off = 128; off > 0; off >>= 1) {
    if (threadIdx.x < off) s[threadIdx.x] += s[threadIdx.x + off];
    __syncthreads();
  }
  if (threadIdx.x == 0) bsum[blockIdx.x] = s[0];
}

// single block, nb <= 256: exclusive-scan bsum in place; total -> *total_out
__global__ void scan_tops_k(int* __restrict__ bsum, int* __restrict__ total_out, int nb) {
  __shared__ int s[256];
  int t = threadIdx.x;
  int v = (t < nb) ? bsum[t] : 0;
  s[t] = v;
  __syncthreads();
  for (int off = 1; off < 256; off <<= 1) {
    int u = (t >= off) ? s[t - off] : 0;
    __syncthreads();
    s[t] += u;
    __syncthreads();
  }
  if (t < nb) bsum[t] = s[t] - v;  // exclusive
  if (t == 255) *total_out = s[255];
}

// per-block scan of its chunk + block offset; cnt may alias cursor (reads first)
__global__ void scan_final_k(const int* __restrict__ cnt, const int* __restrict__ bsum,
                             int* __restrict__ rowptr, int* __restrict__ cursor, int n) {
  __shared__ int s[256];
  int b = blockIdx.x, t = threadIdx.x;
  int idx = b * 256 + t;
  int v = (idx < n) ? cnt[idx] : 0;
  s[t] = v;
  __syncthreads();
  for (int off = 1; off < 256; off <<= 1) {
    int u = (t >= off) ? s[t - off] : 0;
    __syncthreads();
    s[t] += u;
    __syncthreads();
  }
  int base = bsum[b] + s[t] - v;
  if (idx < n) { rowptr[idx] = base; cursor[idx] = base; }
}

__global__ void scatter_k(const int* __restrict__ src, const int* __restrict__ dst,
                          const float* __restrict__ w, const float* __restrict__ dinv,
                          int* __restrict__ cursor, int* __restrict__ csr_src,
                          float* __restrict__ csr_coef, int e) {
  int i = blockIdx.x * blockDim.x + threadIdx.x;
  if (i < e) {
    int d = dst[i];
    int s = src[i];
    int pos = atomicAdd(&cursor[d], 1);
    csr_src[pos] = s;
    csr_coef[pos] = dinv[s] * w[i] * dinv[d];
  }
}

// ---------------- block-tiled GEMM with LDS staging ----------------

template <int FIN, int FOUT, int JT, int JTILES, int RPG, bool BNIN, bool GATHER>
__global__ __launch_bounds__(256) void gemm_tile_k(
    const float* __restrict__ H, const int* __restrict__ xidx,
    const float* __restrict__ scale, const float* __restrict__ shift,
    const float* __restrict__ W, float* __restrict__ out, int n) {
  constexpr int TPC = JT / 4;
  constexpr int G = 256 / TPC;
  constexpr int RT = G * RPG;
  constexpr int C4 = FIN / 4;

  __shared__ float4 Ht[RT * C4];
  __shared__ float4 Wsf[FIN * JT / 4];

  const int r0 = blockIdx.x * RT;
  const int t = threadIdx.x;

  constexpr int NH = RT * C4 / 256;
#pragma unroll
  for (int i = 0; i < NH; ++i) {
    int idx = t + 256 * i;
    int r = idx / C4, c4 = idx % C4;
    int gr = r0 + r;
    if (gr < n) {
      int srow = GATHER ? xidx[gr] : gr;
      float4 v = *(const float4*)(H + (size_t)srow * FIN + c4 * 4);
      if (BNIN) {
        float4 sc = *(const float4*)(scale + c4 * 4);
        float4 sh = *(const float4*)(shift + c4 * 4);
        v.x = fmaxf(v.x * sc.x + sh.x, 0.f);
        v.y = fmaxf(v.y * sc.y + sh.y, 0.f);
        v.z = fmaxf(v.z * sc.z + sh.z, 0.f);
        v.w = fmaxf(v.w * sc.w + sh.w, 0.f);
      }
      Ht[r * C4 + (c4 ^ ((r >> 2) & 7))] = v;
    }
  }

  const int g = t / TPC;
  const int lj = t % TPC;
  const int rbase = g * RPG;

  for (int jb = 0; jb < JTILES; ++jb) {
    constexpr int NW = FIN * JT / 4 / 256;
#pragma unroll
    for (int i = 0; i < NW; ++i) {
      int idx = t + 256 * i;
      int k = idx / TPC, jg = idx % TPC;
      Wsf[idx] = *(const float4*)(W + (size_t)k * FOUT + jb * JT + jg * 4);
    }
    __syncthreads();

    float4 acc[RPG];
#pragma unroll
    for (int rr = 0; rr < RPG; ++rr) acc[rr] = make_float4(0.f, 0.f, 0.f, 0.f);

    for (int k4 = 0; k4 < C4; ++k4) {
      float4 wv0 = Wsf[(k4 * 4 + 0) * TPC + lj];
      float4 wv1 = Wsf[(k4 * 4 + 1) * TPC + lj];
      float4 wv2 = Wsf[(k4 * 4 + 2) * TPC + lj];
      float4 wv3 = Wsf[(k4 * 4 + 3) * TPC + lj];
#pragma unroll
      for (int rr = 0; rr < RPG; ++rr) {
        int r = rbase + rr;
        float4 h = Ht[r * C4 + (k4 ^ ((r >> 2) & 7))];
        acc[rr].x += h.x * wv0.x + h.y * wv1.x + h.z * wv2.x + h.w * wv3.x;
        acc[rr].y += h.x * wv0.y + h.y * wv1.y + h.z * wv2.y + h.w * wv3.y;
        acc[rr].z += h.x * wv0.z + h.y * wv1.z + h.z * wv2.z + h.w * wv3.z;
        acc[rr].w += h.x * wv0.w + h.y * wv1.w + h.z * wv2.w + h.w * wv3.w;
      }
    }

#pragma unroll
    for (int rr = 0; rr < RPG; ++rr) {
      int gr = r0 + rbase + rr;
      if (gr < n)
        *(float4*)(out + (size_t)gr * FOUT + jb * JT + lj * 4) = acc[rr];
    }
    if (jb + 1 < JTILES) __syncthreads();
  }
}

// ---------------- CSR aggregation (gather-only, no atomics) ----------------

template <int FOUT>
__global__ void agg_csr_k(const float* __restrict__ hW, const int* __restrict__ rowptr,
                          const int* __restrict__ csr_src, const float* __restrict__ csr_coef,
                          const float* __restrict__ dinv, const float* __restrict__ b,
                          float* __restrict__ agg, int n) {
  constexpr int TPR = FOUT / 8;
  int gid = blockIdx.x * blockDim.x + threadIdx.x;
  int row = gid / TPR, j = gid % TPR;
  if (row >= n) return;

  const float di = dinv[row];
  const float c0 = di * di;
  const float* hrow = hW + (size_t)row * FOUT + j * 8;
  const float4 h0 = *(const float4*)(hrow);
  const float4 h1 = *(const float4*)(hrow + 4);
  const float4 bb0 = *(const float4*)(b + j * 8);
  const float4 bb1 = *(const float4*)(b + j * 8 + 4);
  float4 a0 = make_float4(h0.x * c0 + bb0.x, h0.y * c0 + bb0.y, h0.z * c0 + bb0.z, h0.w * c0 + bb0.w);
  float4 a1 = make_float4(h1.x * c0 + bb1.x, h1.y * c0 + bb1.y, h1.z * c0 + bb1.z, h1.w * c0 + bb1.w);

  const int e0 = rowptr[row], e1 = rowptr[row + 1];
  int ee = e0;
  for (; ee + 1 < e1; ee += 2) {
    const int s0 = csr_src[ee], s1 = csr_src[ee + 1];
    const float cc0 = csr_coef[ee], cc1 = csr_coef[ee + 1];
    const float* p0 = hW + (size_t)s0 * FOUT + j * 8;
    const float* p1 = hW + (size_t)s1 * FOUT + j * 8;
    const float4 v00 = *(const float4*)(p0);
    const float4 v01 = *(const float4*)(p0 + 4);
    const float4 v10 = *(const float4*)(p1);
    const float4 v11 = *(const float4*)(p1 + 4);
    a0.x += v00.x * cc0; a0.y += v00.y * cc0; a0.z += v00.z * cc0; a0.w += v00.w * cc0;
    a1.x += v01.x * cc0; a1.y += v01.y * cc0; a1.z += v01.z * cc0; a1.w += v01.w * cc0;
    a0.x += v10.x * cc1; a0.y += v10.y * cc1; a0.z += v10.z * cc1; a0.w += v10.w * cc1;
    a1.x += v11.x * cc1; a1.y += v11.y * cc1; a1.z += v11.z * cc1; a1.w += v11.w * cc1;
  }
  if (ee < e1) {
    const int s0 = csr_src[ee];
    const float cc0 = csr_coef[ee];
    const float* p0 = hW + (size_t)s0 * FOUT + j * 8;
    const float4 v00 = *(const float4*)(p0);
    const float4 v01 = *(const float4*)(p0 + 4);
    a0.x += v00.x * cc0; a0.y += v00.y * cc0; a0.z += v00.z * cc0; a0.w += v00.w * cc0;
    a1.x += v01.x * cc0; a1.y += v01.y * cc0; a1.z += v01.z * cc0; a1.w += v01.w * cc0;
  }

  float* orow = agg + (size_t)row * FOUT + j * 8;
  *(float4*)(orow) = a0;
  *(float4*)(orow + 4) = a1;
}

// ---------------- batch norm ----------------

template <int FOUT>
__global__ void bn_stats_k(const float* __restrict__ h, float* __restrict__ gsum,
                           float* __restrict__ gsq, int n) {
  constexpr int COPIES = 256 / FOUT;
  __shared__ float ls[256];
  __shared__ float lq[256];
  const int col = threadIdx.x % FOUT;
  const int cp = threadIdx.x / FOUT;
  float s = 0.f, q = 0.f;
  for (int r = blockIdx.x * COPIES + cp; r < n; r += gridDim.x * COPIES) {
    float v = h[(size_t)r * FOUT + col];
    s += v;
    q += v * v;
  }
  ls[threadIdx.x] = s;
  lq[threadIdx.x] = q;
  __syncthreads();
  if (threadIdx.x < FOUT) {
    float ts = 0.f, tq = 0.f;
#pragma unroll
    for (int c = 0; c < COPIES; ++c) {
      ts += ls[c * FOUT + col];
      tq += lq[c * FOUT + col];
    }
    unsafeAtomicAdd(&gsum[col], ts);
    unsafeAtomicAdd(&gsq[col], tq);
  }
}

// computes scale/shift, then re-zeroes gsum/gsq for the next layer's stats
template <int FOUT>
__global__ void bn_finalize_k(float* __restrict__ gsum, float* __restrict__ gsq,
                              const float* __restrict__ g, const float* __restrict__ be,
                              float* __restrict__ scale, float* __restrict__ shift, int n) {
  int c = threadIdx.x;
  if (c >= FOUT) return;
  float inv_n = 1.0f / (float)n;
  float mu = gsum[c] * inv_n;
  float var = gsq[c] * inv_n - mu * mu;
  float sc = g[c] * rsqrtf(var + BN_EPS);
  scale[c] = sc;
  shift[c] = be[c] - mu * sc;
  gsum[c] = 0.f;
  gsq[c] = 0.f;
}

template <int FOUT, bool RELU>
__global__ void bn_apply_k(const float* __restrict__ in, const float* __restrict__ scale,
                           const float* __restrict__ shift, float* __restrict__ out, int n) {
  constexpr int TPR = FOUT / 4;
  int gid = blockIdx.x * blockDim.x + threadIdx.x;
  int row = gid / TPR, j = gid % TPR;
  if (row >= n) return;
  float4 v = *(const float4*)(in + (size_t)row * FOUT + j * 4);
  float4 sc = *(const float4*)(scale + j * 4);
  float4 sh = *(const float4*)(shift + j * 4);
  float4 o;
  o.x = v.x * sc.x + sh.x;
  o.y = v.y * sc.y + sh.y;
  o.z = v.z * sc.z + sh.z;
  o.w = v.w * sc.w + sh.w;
  if (RELU) {
    o.x = fmaxf(o.x, 0.f);
    o.y = fmaxf(o.y, 0.f);
    o.z = fmaxf(o.z, 0.f);
    o.w = fmaxf(o.w, 0.f);
  }
  *(float4*)(out + (size_t)row * FOUT + j * 4) = o;
}

// ---------------- launch ----------------

static inline size_t pad4(size_t v) { return (v + 3) & ~(size_t)3; }

extern "C" void kernel_launch(void* const* d_in, const int* in_sizes, int n_in,
                              void* d_out, int out_size, void* d_ws, size_t ws_size,
                              hipStream_t stream) {
  const int* x = (const int*)d_in[0];
  const int* ei = (const int*)d_in[1];
  const float* w = (const float*)d_in[2];
  const float* emb = (const float*)d_in[3];
  const float* W1 = (const float*)d_in[4];
  const float* b1 = (const float*)d_in[5];
  const float* g1 = (const float*)d_in[6];
  const float* be1 = (const float*)d_in[7];
  const float* W2 = (const float*)d_in[8];
  const float* b2 = (const float*)d_in[9];
  const float* g2 = (const float*)d_in[10];
  const float* be2 = (const float*)d_in[11];
  const float* W3 = (const float*)d_in[12];
  const float* b3 = (const float*)d_in[13];
  const float* g3 = (const float*)d_in[14];
  const float* be3 = (const float*)d_in[15];

  const int n = in_sizes[0];
  const int e = in_sizes[2];
  const int* src = ei;
  const int* dst = ei + e;

  float* ws = (float*)d_ws;
  size_t off = 0;
  float* bufA = ws + off; off += pad4((size_t)n * 128);
  float* bufB = ws + off; off += pad4((size_t)n * 128);
  float* dinv = ws + off; off += pad4(n);
  int* rowptr = (int*)(ws + off); off += pad4(n + 1);
  int* cursor = (int*)(ws + off); off += pad4(n);
  int* csr_src = (int*)(ws + off); off += pad4(e);
  float* csr_coef = ws + off; off += pad4(e);
  float* gsum = ws + off; off += 128;   // gsum+gsq contiguous (zeroed together)
  float* gsq = ws + off; off += 128;
  float* scale = ws + off; off += 128;
  float* shift = ws + off; off += 128;
  int* bsum = (int*)(ws + off); off += 256;

  const int B = 256;
  dim3 blk(B);
  const int nb = (n + 255) / 256;  // scan blocks (<=256 required; n=50k -> 196)

  // CSR build (shared by all layers)
  zero_graph_k<<<(n + B - 1) / B, blk, 0, stream>>>(cursor, dinv, gsum, n);
  hist_k<<<(e + B - 1) / B, blk, 0, stream>>>(dst, w, cursor, dinv, e);
  dinv_k<<<(n + B - 1) / B, blk, 0, stream>>>(dinv, n);
  scan_partial_k<<<nb, blk, 0, stream>>>(cursor, bsum, n);
  scan_tops_k<<<1, blk, 0, stream>>>(bsum, rowptr + n, nb);
  scan_final_k<<<nb, blk, 0, stream>>>(cursor, bsum, rowptr, cursor, n);
  scatter_k<<<(e + B - 1) / B, blk, 0, stream>>>(src, dst, w, dinv, cursor, csr_src, csr_coef, e);

  const int gx = (n + 63) / 64;  // RT = 64 for all layers

  // ---- layer 1: gemm(emb[x]) -> bufA; agg -> bufB; stats
  gemm_tile_k<128, 128, 64, 2, 4, false, true><<<gx, blk, 0, stream>>>(emb, x, nullptr, nullptr, W1, bufA, n);
  agg_csr_k<128><<<((size_t)n * 16 + B - 1) / B, blk, 0, stream>>>(bufA, rowptr, csr_src, csr_coef, dinv, b1, bufB, n);
  bn_stats_k<128><<<256, blk, 0, stream>>>(bufB, gsum, gsq, n);
  bn_finalize_k<128><<<1, 128, 0, stream>>>(gsum, gsq, g1, be1, scale, shift, n);

  // ---- layer 2: gemm(BN+ReLU(bufB)) -> bufA; agg -> bufB; stats
  gemm_tile_k<128, 64, 64, 1, 4, true, false><<<gx, blk, 0, stream>>>(bufB, nullptr, scale, shift, W2, bufA, n);
  agg_csr_k<64><<<((size_t)n * 8 + B - 1) / B, blk, 0, stream>>>(bufA, rowptr, csr_src, csr_coef, dinv, b2, bufB, n);
  bn_stats_k<64><<<256, blk, 0, stream>>>(bufB, gsum, gsq, n);
  bn_finalize_k<64><<<1, 64, 0, stream>>>(gsum, gsq, g2, be2, scale, shift, n);

  // ---- layer 3: gemm(BN+ReLU(bufB)) -> bufA; agg -> bufB; BN -> d_out
  gemm_tile_k<64, 32, 32, 1, 2, true, false><<<gx, blk, 0, stream>>>(bufB, nullptr, scale, shift, W3, bufA, n);
  agg_csr_k<32><<<((size_t)n * 4 + B - 1) / B, blk, 0, stream>>>(bufA, rowptr, csr_src, csr_coef, dinv, b3, bufB, n);
  bn_stats_k<32><<<256, blk, 0, stream>>>(bufB, gsum, gsq, n);
  bn_finalize_k<32><<<1, 32, 0, stream>>>(gsum, gsq, g3, be3, scale, shift, n);
  bn_apply_k<32, false><<<((size_t)n * 8 + B - 1) / B, blk, 0, stream>>>(bufB, scale, shift, (float*)d_out, n);
}

// Round 6
// 361.827 us; speedup vs baseline: 5.4434x; 1.1397x over previous
//
#include <hip/hip_runtime.h>

#define BN_EPS 1e-5f
#define FIXSCALE 16777216.0f            // 2^24
#define FIXINV   5.9604644775390625e-08 // 2^-24
#define LOWMASK  0xFFFFFFFFFFULL        // low 40 bits

// ---------------- graph preprocessing (CSR by dst, 1 atomic/edge) ----------------

__global__ void zero_graph_k(unsigned long long* __restrict__ packed,
                             float* __restrict__ gstats, int* __restrict__ ctr, int n) {
  int i = blockIdx.x * blockDim.x + threadIdx.x;
  if (i < n) packed[i] = 0ULL;
  if (i < 256) gstats[i] = 0.f;  // gsum[128] + gsq[128]
  if (i == 0) *ctr = 0;
}

// packed[d] += (1<<40) | fix(w); rank = old count field
__global__ void hist64_k(const int* __restrict__ dst, const float* __restrict__ w,
                         unsigned long long* __restrict__ packed, int* __restrict__ rank, int e) {
  int i = blockIdx.x * blockDim.x + threadIdx.x;
  if (i < e) {
    unsigned long long fw = (unsigned long long)__float2uint_rn(w[i] * FIXSCALE);
    unsigned long long old = atomicAdd(&packed[dst[i]], (1ULL << 40) | fw);
    rank[i] = (int)(old >> 40);
  }
}

// per-block reduce of counts -> bsum; also dinv[i] = rsqrt(1 + wsum)
__global__ void scan_partial_k(const unsigned long long* __restrict__ packed,
                               int* __restrict__ bsum, float* __restrict__ dinv, int n) {
  __shared__ int s[256];
  int idx = blockIdx.x * 256 + threadIdx.x;
  unsigned long long p = (idx < n) ? packed[idx] : 0ULL;
  if (idx < n)
    dinv[idx] = rsqrtf(1.0f + (float)((double)(p & LOWMASK) * FIXINV));
  s[threadIdx.x] = (int)(p >> 40);
  __syncthreads();
  for (int off = 128; off > 0; off >>= 1) {
    if (threadIdx.x < off) s[threadIdx.x] += s[threadIdx.x + off];
    __syncthreads();
  }
  if (threadIdx.x == 0) bsum[blockIdx.x] = s[0];
}

// single block, nb <= 256: exclusive-scan bsum in place; total -> *total_out
__global__ void scan_tops_k(int* __restrict__ bsum, int* __restrict__ total_out, int nb) {
  __shared__ int s[256];
  int t = threadIdx.x;
  int v = (t < nb) ? bsum[t] : 0;
  s[t] = v;
  __syncthreads();
  for (int off = 1; off < 256; off <<= 1) {
    int u = (t >= off) ? s[t - off] : 0;
    __syncthreads();
    s[t] += u;
    __syncthreads();
  }
  if (t < nb) bsum[t] = s[t] - v;  // exclusive
  if (t == 255) *total_out = s[255];
}

// per-block scan of counts + block offset -> rowptr
__global__ void scan_final_k(const unsigned long long* __restrict__ packed,
                             const int* __restrict__ bsum, int* __restrict__ rowptr, int n) {
  __shared__ int s[256];
  int b = blockIdx.x, t = threadIdx.x;
  int idx = b * 256 + t;
  int v = (idx < n) ? (int)(packed[idx] >> 40) : 0;
  s[t] = v;
  __syncthreads();
  for (int off = 1; off < 256; off <<= 1) {
    int u = (t >= off) ? s[t - off] : 0;
    __syncthreads();
    s[t] += u;
    __syncthreads();
  }
  if (idx < n) rowptr[idx] = bsum[b] + s[t] - v;
}

// atomic-free scatter: pos = rowptr[dst] + rank; csr entry = {src, coef}
__global__ void scatter_nb_k(const int* __restrict__ src, const int* __restrict__ dst,
                             const float* __restrict__ w, const int* __restrict__ rank,
                             const float* __restrict__ dinv, const int* __restrict__ rowptr,
                             int2* __restrict__ csr, int e) {
  int i = blockIdx.x * blockDim.x + threadIdx.x;
  if (i < e) {
    int d = dst[i], s = src[i];
    int pos = rowptr[d] + rank[i];
    float c = dinv[s] * w[i] * dinv[d];
    csr[pos] = make_int2(s, __float_as_int(c));
  }
}

// ---------------- block-tiled GEMM with LDS staging ----------------

template <int FIN, int FOUT, int JT, int JTILES, int RPG, bool BNIN, bool GATHER>
__global__ __launch_bounds__(256) void gemm_tile_k(
    const float* __restrict__ H, const int* __restrict__ xidx,
    const float* __restrict__ scale, const float* __restrict__ shift,
    const float* __restrict__ W, float* __restrict__ out, int n) {
  constexpr int TPC = JT / 4;
  constexpr int G = 256 / TPC;
  constexpr int RT = G * RPG;
  constexpr int C4 = FIN / 4;

  __shared__ float4 Ht[RT * C4];
  __shared__ float4 Wsf[FIN * JT / 4];

  const int r0 = blockIdx.x * RT;
  const int t = threadIdx.x;

  constexpr int NH = RT * C4 / 256;
#pragma unroll
  for (int i = 0; i < NH; ++i) {
    int idx = t + 256 * i;
    int r = idx / C4, c4 = idx % C4;
    int gr = r0 + r;
    if (gr < n) {
      int srow = GATHER ? xidx[gr] : gr;
      float4 v = *(const float4*)(H + (size_t)srow * FIN + c4 * 4);
      if (BNIN) {
        float4 sc = *(const float4*)(scale + c4 * 4);
        float4 sh = *(const float4*)(shift + c4 * 4);
        v.x = fmaxf(v.x * sc.x + sh.x, 0.f);
        v.y = fmaxf(v.y * sc.y + sh.y, 0.f);
        v.z = fmaxf(v.z * sc.z + sh.z, 0.f);
        v.w = fmaxf(v.w * sc.w + sh.w, 0.f);
      }
      Ht[r * C4 + (c4 ^ ((r >> 2) & 7))] = v;
    }
  }

  const int g = t / TPC;
  const int lj = t % TPC;
  const int rbase = g * RPG;

  for (int jb = 0; jb < JTILES; ++jb) {
    constexpr int NW = FIN * JT / 4 / 256;
#pragma unroll
    for (int i = 0; i < NW; ++i) {
      int idx = t + 256 * i;
      int k = idx / TPC, jg = idx % TPC;
      Wsf[idx] = *(const float4*)(W + (size_t)k * FOUT + jb * JT + jg * 4);
    }
    __syncthreads();

    float4 acc[RPG];
#pragma unroll
    for (int rr = 0; rr < RPG; ++rr) acc[rr] = make_float4(0.f, 0.f, 0.f, 0.f);

    for (int k4 = 0; k4 < C4; ++k4) {
      float4 wv0 = Wsf[(k4 * 4 + 0) * TPC + lj];
      float4 wv1 = Wsf[(k4 * 4 + 1) * TPC + lj];
      float4 wv2 = Wsf[(k4 * 4 + 2) * TPC + lj];
      float4 wv3 = Wsf[(k4 * 4 + 3) * TPC + lj];
#pragma unroll
      for (int rr = 0; rr < RPG; ++rr) {
        int r = rbase + rr;
        float4 h = Ht[r * C4 + (k4 ^ ((r >> 2) & 7))];
        acc[rr].x += h.x * wv0.x + h.y * wv1.x + h.z * wv2.x + h.w * wv3.x;
        acc[rr].y += h.x * wv0.y + h.y * wv1.y + h.z * wv2.y + h.w * wv3.y;
        acc[rr].z += h.x * wv0.z + h.y * wv1.z + h.z * wv2.z + h.w * wv3.z;
        acc[rr].w += h.x * wv0.w + h.y * wv1.w + h.z * wv2.w + h.w * wv3.w;
      }
    }

#pragma unroll
    for (int rr = 0; rr < RPG; ++rr) {
      int gr = r0 + rbase + rr;
      if (gr < n)
        *(float4*)(out + (size_t)gr * FOUT + jb * JT + lj * 4) = acc[rr];
    }
    if (jb + 1 < JTILES) __syncthreads();
  }
}

// ---------------- CSR aggregation (gather-only, no atomics) ----------------

template <int FOUT>
__global__ void agg_csr_k(const float* __restrict__ hW, const int* __restrict__ rowptr,
                          const int2* __restrict__ csr, const float* __restrict__ dinv,
                          const float* __restrict__ b, float* __restrict__ agg, int n) {
  constexpr int TPR = FOUT / 8;
  int gid = blockIdx.x * blockDim.x + threadIdx.x;
  int row = gid / TPR, j = gid % TPR;
  if (row >= n) return;

  const float di = dinv[row];
  const float c0 = di * di;
  const float* hrow = hW + (size_t)row * FOUT + j * 8;
  const float4 h0 = *(const float4*)(hrow);
  const float4 h1 = *(const float4*)(hrow + 4);
  const float4 bb0 = *(const float4*)(b + j * 8);
  const float4 bb1 = *(const float4*)(b + j * 8 + 4);
  float4 a0 = make_float4(h0.x * c0 + bb0.x, h0.y * c0 + bb0.y, h0.z * c0 + bb0.z, h0.w * c0 + bb0.w);
  float4 a1 = make_float4(h1.x * c0 + bb1.x, h1.y * c0 + bb1.y, h1.z * c0 + bb1.z, h1.w * c0 + bb1.w);

  const int e0 = rowptr[row], e1 = rowptr[row + 1];
  int ee = e0;
  for (; ee + 1 < e1; ee += 2) {
    const int2 ed0 = csr[ee];
    const int2 ed1 = csr[ee + 1];
    const float cc0 = __int_as_float(ed0.y);
    const float cc1 = __int_as_float(ed1.y);
    const float* p0 = hW + (size_t)ed0.x * FOUT + j * 8;
    const float* p1 = hW + (size_t)ed1.x * FOUT + j * 8;
    const float4 v00 = *(const float4*)(p0);
    const float4 v01 = *(const float4*)(p0 + 4);
    const float4 v10 = *(const float4*)(p1);
    const float4 v11 = *(const float4*)(p1 + 4);
    a0.x += v00.x * cc0; a0.y += v00.y * cc0; a0.z += v00.z * cc0; a0.w += v00.w * cc0;
    a1.x += v01.x * cc0; a1.y += v01.y * cc0; a1.z += v01.z * cc0; a1.w += v01.w * cc0;
    a0.x += v10.x * cc1; a0.y += v10.y * cc1; a0.z += v10.z * cc1; a0.w += v10.w * cc1;
    a1.x += v11.x * cc1; a1.y += v11.y * cc1; a1.z += v11.z * cc1; a1.w += v11.w * cc1;
  }
  if (ee < e1) {
    const int2 ed0 = csr[ee];
    const float cc0 = __int_as_float(ed0.y);
    const float* p0 = hW + (size_t)ed0.x * FOUT + j * 8;
    const float4 v00 = *(const float4*)(p0);
    const float4 v01 = *(const float4*)(p0 + 4);
    a0.x += v00.x * cc0; a0.y += v00.y * cc0; a0.z += v00.z * cc0; a0.w += v00.w * cc0;
    a1.x += v01.x * cc0; a1.y += v01.y * cc0; a1.z += v01.z * cc0; a1.w += v01.w * cc0;
  }

  float* orow = agg + (size_t)row * FOUT + j * 8;
  *(float4*)(orow) = a0;
  *(float4*)(orow + 4) = a1;
}

// ---------------- batch norm: stats + finalize fused (last-block-done) ----------------

template <int FOUT>
__global__ void bn_stats_fused_k(const float* __restrict__ h, float* __restrict__ gsum,
                                 float* __restrict__ gsq, const float* __restrict__ g,
                                 const float* __restrict__ be, float* __restrict__ scale,
                                 float* __restrict__ shift, int* __restrict__ ctr, int n) {
  constexpr int COPIES = 256 / FOUT;
  __shared__ float ls[256];
  __shared__ float lq[256];
  __shared__ int lastdone;
  const int col = threadIdx.x % FOUT;
  const int cp = threadIdx.x / FOUT;
  float s = 0.f, q = 0.f;
  for (int r = blockIdx.x * COPIES + cp; r < n; r += gridDim.x * COPIES) {
    float v = h[(size_t)r * FOUT + col];
    s += v;
    q += v * v;
  }
  ls[threadIdx.x] = s;
  lq[threadIdx.x] = q;
  __syncthreads();
  if (threadIdx.x < FOUT) {
    float ts = 0.f, tq = 0.f;
#pragma unroll
    for (int c = 0; c < COPIES; ++c) {
      ts += ls[c * FOUT + col];
      tq += lq[c * FOUT + col];
    }
    unsafeAtomicAdd(&gsum[col], ts);
    unsafeAtomicAdd(&gsq[col], tq);
  }
  __threadfence();
  if (threadIdx.x == 0)
    lastdone = (atomicAdd(ctr, 1) == (int)gridDim.x - 1);
  __syncthreads();
  if (lastdone) {
    if (threadIdx.x < FOUT) {
      int c = threadIdx.x;
      // coherent reads of atomically-accumulated stats (XCD-safe)
      float ts = unsafeAtomicAdd(&gsum[c], 0.f);
      float tq = unsafeAtomicAdd(&gsq[c], 0.f);
      float inv_n = 1.0f / (float)n;
      float mu = ts * inv_n;
      float var = tq * inv_n - mu * mu;
      float sc = g[c] * rsqrtf(var + BN_EPS);
      scale[c] = sc;
      shift[c] = be[c] - mu * sc;
      atomicExch(&gsum[c], 0.f);  // reset for next layer (coherent)
      atomicExch(&gsq[c], 0.f);
    }
    if (threadIdx.x == 0) atomicExch(ctr, 0);
  }
}

template <int FOUT, bool RELU>
__global__ void bn_apply_k(const float* __restrict__ in, const float* __restrict__ scale,
                           const float* __restrict__ shift, float* __restrict__ out, int n) {
  constexpr int TPR = FOUT / 4;
  int gid = blockIdx.x * blockDim.x + threadIdx.x;
  int row = gid / TPR, j = gid % TPR;
  if (row >= n) return;
  float4 v = *(const float4*)(in + (size_t)row * FOUT + j * 4);
  float4 sc = *(const float4*)(scale + j * 4);
  float4 sh = *(const float4*)(shift + j * 4);
  float4 o;
  o.x = v.x * sc.x + sh.x;
  o.y = v.y * sc.y + sh.y;
  o.z = v.z * sc.z + sh.z;
  o.w = v.w * sc.w + sh.w;
  if (RELU) {
    o.x = fmaxf(o.x, 0.f);
    o.y = fmaxf(o.y, 0.f);
    o.z = fmaxf(o.z, 0.f);
    o.w = fmaxf(o.w, 0.f);
  }
  *(float4*)(out + (size_t)row * FOUT + j * 4) = o;
}

// ---------------- launch ----------------

static inline size_t pad4(size_t v) { return (v + 3) & ~(size_t)3; }

extern "C" void kernel_launch(void* const* d_in, const int* in_sizes, int n_in,
                              void* d_out, int out_size, void* d_ws, size_t ws_size,
                              hipStream_t stream) {
  const int* x = (const int*)d_in[0];
  const int* ei = (const int*)d_in[1];
  const float* w = (const float*)d_in[2];
  const float* emb = (const float*)d_in[3];
  const float* W1 = (const float*)d_in[4];
  const float* b1 = (const float*)d_in[5];
  const float* g1 = (const float*)d_in[6];
  const float* be1 = (const float*)d_in[7];
  const float* W2 = (const float*)d_in[8];
  const float* b2 = (const float*)d_in[9];
  const float* g2 = (const float*)d_in[10];
  const float* be2 = (const float*)d_in[11];
  const float* W3 = (const float*)d_in[12];
  const float* b3 = (const float*)d_in[13];
  const float* g3 = (const float*)d_in[14];
  const float* be3 = (const float*)d_in[15];

  const int n = in_sizes[0];
  const int e = in_sizes[2];
  const int* src = ei;
  const int* dst = ei + e;

  float* ws = (float*)d_ws;
  size_t off = 0;
  float* bufA = ws + off; off += pad4((size_t)n * 128);
  float* bufB = ws + off; off += pad4((size_t)n * 128);
  unsigned long long* packed = (unsigned long long*)(ws + off); off += pad4((size_t)n * 2);
  float* dinv = ws + off; off += pad4(n);
  int* rowptr = (int*)(ws + off); off += pad4(n + 1);
  int* rank = (int*)(ws + off); off += pad4(e);
  int2* csr = (int2*)(ws + off); off += pad4((size_t)e * 2);
  float* gsum = ws + off; off += 128;   // gsum+gsq contiguous (zeroed together)
  float* gsq = ws + off; off += 128;
  float* scale = ws + off; off += 128;
  float* shift = ws + off; off += 128;
  int* bsum = (int*)(ws + off); off += 256;
  int* ctr = (int*)(ws + off); off += 4;

  const int B = 256;
  dim3 blk(B);
  const int nb = (n + 255) / 256;  // scan blocks (<=256 required; n=50k -> 196)

  // CSR build (shared by all layers; 1 atomic per edge total)
  zero_graph_k<<<(n + B - 1) / B, blk, 0, stream>>>(packed, gsum, ctr, n);
  hist64_k<<<(e + B - 1) / B, blk, 0, stream>>>(dst, w, packed, rank, e);
  scan_partial_k<<<nb, blk, 0, stream>>>(packed, bsum, dinv, n);
  scan_tops_k<<<1, blk, 0, stream>>>(bsum, rowptr + n, nb);
  scan_final_k<<<nb, blk, 0, stream>>>(packed, bsum, rowptr, n);
  scatter_nb_k<<<(e + B - 1) / B, blk, 0, stream>>>(src, dst, w, rank, dinv, rowptr, csr, e);

  const int gx = (n + 63) / 64;  // RT = 64 for all layers

  // ---- layer 1: gemm(emb[x]) -> bufA; agg -> bufB; stats+finalize
  gemm_tile_k<128, 128, 64, 2, 4, false, true><<<gx, blk, 0, stream>>>(emb, x, nullptr, nullptr, W1, bufA, n);
  agg_csr_k<128><<<((size_t)n * 16 + B - 1) / B, blk, 0, stream>>>(bufA, rowptr, csr, dinv, b1, bufB, n);
  bn_stats_fused_k<128><<<256, blk, 0, stream>>>(bufB, gsum, gsq, g1, be1, scale, shift, ctr, n);

  // ---- layer 2: gemm(BN+ReLU(bufB)) -> bufA; agg -> bufB; stats+finalize
  gemm_tile_k<128, 64, 64, 1, 4, true, false><<<gx, blk, 0, stream>>>(bufB, nullptr, scale, shift, W2, bufA, n);
  agg_csr_k<64><<<((size_t)n * 8 + B - 1) / B, blk, 0, stream>>>(bufA, rowptr, csr, dinv, b2, bufB, n);
  bn_stats_fused_k<64><<<256, blk, 0, stream>>>(bufB, gsum, gsq, g2, be2, scale, shift, ctr, n);

  // ---- layer 3: gemm(BN+ReLU(bufB)) -> bufA; agg -> bufB; BN -> d_out
  gemm_tile_k<64, 32, 32, 1, 2, true, false><<<gx, blk, 0, stream>>>(bufB, nullptr, scale, shift, W3, bufA, n);
  agg_csr_k<32><<<((size_t)n * 4 + B - 1) / B, blk, 0, stream>>>(bufA, rowptr, csr, dinv, b3, bufB, n);
  bn_stats_fused_k<32><<<256, blk, 0, stream>>>(bufB, gsum, gsq, g3, be3, scale, shift, ctr, n);
  bn_apply_k<32, false><<<((size_t)n * 8 + B - 1) / B, blk, 0, stream>>>(bufB, scale, shift, (float*)d_out, n);
}

// Round 7
// 324.835 us; speedup vs baseline: 6.0633x; 1.1139x over previous
//
#include <hip/hip_runtime.h>
#include <hip/hip_bf16.h>

#define BN_EPS 1e-5f
#define FIXSCALE 16777216.0f            // 2^24
#define FIXINV   5.9604644775390625e-08 // 2^-24
#define LOWMASK  0xFFFFFFFFFFULL        // low 40 bits

// bf16 helpers: pair packed in uint32 (lo = elem0, hi = elem1)
__device__ __forceinline__ unsigned int pk_bf2(float a, float b) {
  return (unsigned int)__bfloat16_as_ushort(__float2bfloat16(a)) |
         ((unsigned int)__bfloat16_as_ushort(__float2bfloat16(b)) << 16);
}
__device__ __forceinline__ float bf_lo(unsigned int u) { return __uint_as_float(u << 16); }
__device__ __forceinline__ float bf_hi(unsigned int u) { return __uint_as_float(u & 0xFFFF0000u); }

// ---------------- graph preprocessing (CSR by dst, 1 atomic/edge) ----------------

__global__ void zero_graph_k(unsigned long long* __restrict__ packed,
                             float* __restrict__ gstats, int* __restrict__ ctr, int n) {
  int i = blockIdx.x * blockDim.x + threadIdx.x;
  if (i < n) packed[i] = 0ULL;
  if (i < 256) gstats[i] = 0.f;  // gsum[128] + gsq[128]
  if (i == 0) *ctr = 0;
}

// packed[d] += (1<<40) | fix(w); rank = old count field
__global__ void hist64_k(const int* __restrict__ dst, const float* __restrict__ w,
                         unsigned long long* __restrict__ packed, int* __restrict__ rank, int e) {
  int i = blockIdx.x * blockDim.x + threadIdx.x;
  if (i < e) {
    unsigned long long fw = (unsigned long long)__float2uint_rn(w[i] * FIXSCALE);
    unsigned long long old = atomicAdd(&packed[dst[i]], (1ULL << 40) | fw);
    rank[i] = (int)(old >> 40);
  }
}

// per-block reduce of counts -> bsum; also dinv[i] = rsqrt(1 + wsum)
__global__ void scan_partial_k(const unsigned long long* __restrict__ packed,
                               int* __restrict__ bsum, float* __restrict__ dinv, int n) {
  __shared__ int s[256];
  int idx = blockIdx.x * 256 + threadIdx.x;
  unsigned long long p = (idx < n) ? packed[idx] : 0ULL;
  if (idx < n)
    dinv[idx] = rsqrtf(1.0f + (float)((double)(p & LOWMASK) * FIXINV));
  s[threadIdx.x] = (int)(p >> 40);
  __syncthreads();
  for (int off = 128; off > 0; off >>= 1) {
    if (threadIdx.x < off) s[threadIdx.x] += s[threadIdx.x + off];
    __syncthreads();
  }
  if (threadIdx.x == 0) bsum[blockIdx.x] = s[0];
}

// single block, nb <= 256: exclusive-scan bsum in place; total -> *total_out
__global__ void scan_tops_k(int* __restrict__ bsum, int* __restrict__ total_out, int nb) {
  __shared__ int s[256];
  int t = threadIdx.x;
  int v = (t < nb) ? bsum[t] : 0;
  s[t] = v;
  __syncthreads();
  for (int off = 1; off < 256; off <<= 1) {
    int u = (t >= off) ? s[t - off] : 0;
    __syncthreads();
    s[t] += u;
    __syncthreads();
  }
  if (t < nb) bsum[t] = s[t] - v;  // exclusive
  if (t == 255) *total_out = s[255];
}

// per-block scan of counts + block offset -> rowptr
__global__ void scan_final_k(const unsigned long long* __restrict__ packed,
                             const int* __restrict__ bsum, int* __restrict__ rowptr, int n) {
  __shared__ int s[256];
  int b = blockIdx.x, t = threadIdx.x;
  int idx = b * 256 + t;
  int v = (idx < n) ? (int)(packed[idx] >> 40) : 0;
  s[t] = v;
  __syncthreads();
  for (int off = 1; off < 256; off <<= 1) {
    int u = (t >= off) ? s[t - off] : 0;
    __syncthreads();
    s[t] += u;
    __syncthreads();
  }
  if (idx < n) rowptr[idx] = bsum[b] + s[t] - v;
}

// atomic-free scatter: pos = rowptr[dst] + rank; csr entry = {src, coef}
__global__ void scatter_nb_k(const int* __restrict__ src, const int* __restrict__ dst,
                             const float* __restrict__ w, const int* __restrict__ rank,
                             const float* __restrict__ dinv, const int* __restrict__ rowptr,
                             int2* __restrict__ csr, int e) {
  int i = blockIdx.x * blockDim.x + threadIdx.x;
  if (i < e) {
    int d = dst[i], s = src[i];
    int pos = rowptr[d] + rank[i];
    float c = dinv[s] * w[i] * dinv[d];
    csr[pos] = make_int2(s, __float_as_int(c));
  }
}

// ---------------- block-tiled GEMM with LDS staging, bf16 output ----------------

template <int FIN, int FOUT, int JT, int JTILES, int RPG, bool BNIN, bool GATHER>
__global__ __launch_bounds__(256) void gemm_tile_k(
    const float* __restrict__ H, const int* __restrict__ xidx,
    const float* __restrict__ scale, const float* __restrict__ shift,
    const float* __restrict__ W, unsigned short* __restrict__ out, int n) {
  constexpr int TPC = JT / 4;
  constexpr int G = 256 / TPC;
  constexpr int RT = G * RPG;
  constexpr int C4 = FIN / 4;

  __shared__ float4 Ht[RT * C4];
  __shared__ float4 Wsf[FIN * JT / 4];

  const int r0 = blockIdx.x * RT;
  const int t = threadIdx.x;

  constexpr int NH = RT * C4 / 256;
#pragma unroll
  for (int i = 0; i < NH; ++i) {
    int idx = t + 256 * i;
    int r = idx / C4, c4 = idx % C4;
    int gr = r0 + r;
    if (gr < n) {
      int srow = GATHER ? xidx[gr] : gr;
      float4 v = *(const float4*)(H + (size_t)srow * FIN + c4 * 4);
      if (BNIN) {
        float4 sc = *(const float4*)(scale + c4 * 4);
        float4 sh = *(const float4*)(shift + c4 * 4);
        v.x = fmaxf(v.x * sc.x + sh.x, 0.f);
        v.y = fmaxf(v.y * sc.y + sh.y, 0.f);
        v.z = fmaxf(v.z * sc.z + sh.z, 0.f);
        v.w = fmaxf(v.w * sc.w + sh.w, 0.f);
      }
      Ht[r * C4 + (c4 ^ ((r >> 2) & 7))] = v;
    }
  }

  const int g = t / TPC;
  const int lj = t % TPC;
  const int rbase = g * RPG;

  for (int jb = 0; jb < JTILES; ++jb) {
    constexpr int NW = FIN * JT / 4 / 256;
#pragma unroll
    for (int i = 0; i < NW; ++i) {
      int idx = t + 256 * i;
      int k = idx / TPC, jg = idx % TPC;
      Wsf[idx] = *(const float4*)(W + (size_t)k * FOUT + jb * JT + jg * 4);
    }
    __syncthreads();

    float4 acc[RPG];
#pragma unroll
    for (int rr = 0; rr < RPG; ++rr) acc[rr] = make_float4(0.f, 0.f, 0.f, 0.f);

    for (int k4 = 0; k4 < C4; ++k4) {
      float4 wv0 = Wsf[(k4 * 4 + 0) * TPC + lj];
      float4 wv1 = Wsf[(k4 * 4 + 1) * TPC + lj];
      float4 wv2 = Wsf[(k4 * 4 + 2) * TPC + lj];
      float4 wv3 = Wsf[(k4 * 4 + 3) * TPC + lj];
#pragma unroll
      for (int rr = 0; rr < RPG; ++rr) {
        int r = rbase + rr;
        float4 h = Ht[r * C4 + (k4 ^ ((r >> 2) & 7))];
        acc[rr].x += h.x * wv0.x + h.y * wv1.x + h.z * wv2.x + h.w * wv3.x;
        acc[rr].y += h.x * wv0.y + h.y * wv1.y + h.z * wv2.y + h.w * wv3.y;
        acc[rr].z += h.x * wv0.z + h.y * wv1.z + h.z * wv2.z + h.w * wv3.z;
        acc[rr].w += h.x * wv0.w + h.y * wv1.w + h.z * wv2.w + h.w * wv3.w;
      }
    }

#pragma unroll
    for (int rr = 0; rr < RPG; ++rr) {
      int gr = r0 + rbase + rr;
      if (gr < n) {
        uint2 pkd = make_uint2(pk_bf2(acc[rr].x, acc[rr].y), pk_bf2(acc[rr].z, acc[rr].w));
        *(uint2*)(out + (size_t)gr * FOUT + jb * JT + lj * 4) = pkd;
      }
    }
    if (jb + 1 < JTILES) __syncthreads();
  }
}

// ---------------- CSR aggregation (bf16 gather, f32 accumulate) ----------------

template <int FOUT>
__global__ void agg_csr_k(const unsigned short* __restrict__ hW, const int* __restrict__ rowptr,
                          const int2* __restrict__ csr, const float* __restrict__ dinv,
                          const float* __restrict__ b, float* __restrict__ agg, int n) {
  constexpr int TPR = FOUT / 8;
  int gid = blockIdx.x * blockDim.x + threadIdx.x;
  int row = gid / TPR, j = gid % TPR;
  if (row >= n) return;

  const float di = dinv[row];
  const float c0 = di * di;
  const uint4 hu = *(const uint4*)(hW + (size_t)row * FOUT + j * 8);
  const float4 bb0 = *(const float4*)(b + j * 8);
  const float4 bb1 = *(const float4*)(b + j * 8 + 4);
  float4 a0 = make_float4(bf_lo(hu.x) * c0 + bb0.x, bf_hi(hu.x) * c0 + bb0.y,
                          bf_lo(hu.y) * c0 + bb0.z, bf_hi(hu.y) * c0 + bb0.w);
  float4 a1 = make_float4(bf_lo(hu.z) * c0 + bb1.x, bf_hi(hu.z) * c0 + bb1.y,
                          bf_lo(hu.w) * c0 + bb1.z, bf_hi(hu.w) * c0 + bb1.w);

  const int e0 = rowptr[row], e1 = rowptr[row + 1];
  int ee = e0;
  for (; ee + 1 < e1; ee += 2) {
    const int2 ed0 = csr[ee];
    const int2 ed1 = csr[ee + 1];
    const float cc0 = __int_as_float(ed0.y);
    const float cc1 = __int_as_float(ed1.y);
    const uint4 u0 = *(const uint4*)(hW + (size_t)ed0.x * FOUT + j * 8);
    const uint4 u1 = *(const uint4*)(hW + (size_t)ed1.x * FOUT + j * 8);
    a0.x += bf_lo(u0.x) * cc0; a0.y += bf_hi(u0.x) * cc0;
    a0.z += bf_lo(u0.y) * cc0; a0.w += bf_hi(u0.y) * cc0;
    a1.x += bf_lo(u0.z) * cc0; a1.y += bf_hi(u0.z) * cc0;
    a1.z += bf_lo(u0.w) * cc0; a1.w += bf_hi(u0.w) * cc0;
    a0.x += bf_lo(u1.x) * cc1; a0.y += bf_hi(u1.x) * cc1;
    a0.z += bf_lo(u1.y) * cc1; a0.w += bf_hi(u1.y) * cc1;
    a1.x += bf_lo(u1.z) * cc1; a1.y += bf_hi(u1.z) * cc1;
    a1.z += bf_lo(u1.w) * cc1; a1.w += bf_hi(u1.w) * cc1;
  }
  if (ee < e1) {
    const int2 ed0 = csr[ee];
    const float cc0 = __int_as_float(ed0.y);
    const uint4 u0 = *(const uint4*)(hW + (size_t)ed0.x * FOUT + j * 8);
    a0.x += bf_lo(u0.x) * cc0; a0.y += bf_hi(u0.x) * cc0;
    a0.z += bf_lo(u0.y) * cc0; a0.w += bf_hi(u0.y) * cc0;
    a1.x += bf_lo(u0.z) * cc0; a1.y += bf_hi(u0.z) * cc0;
    a1.z += bf_lo(u0.w) * cc0; a1.w += bf_hi(u0.w) * cc0;
  }

  float* orow = agg + (size_t)row * FOUT + j * 8;
  *(float4*)(orow) = a0;
  *(float4*)(orow + 4) = a1;
}

// ---------------- batch norm: stats + finalize fused (last-block-done) ----------------

template <int FOUT>
__global__ void bn_stats_fused_k(const float* __restrict__ h, float* __restrict__ gsum,
                                 float* __restrict__ gsq, const float* __restrict__ g,
                                 const float* __restrict__ be, float* __restrict__ scale,
                                 float* __restrict__ shift, int* __restrict__ ctr, int n) {
  constexpr int COPIES = 256 / FOUT;
  __shared__ float ls[256];
  __shared__ float lq[256];
  __shared__ int lastdone;
  const int col = threadIdx.x % FOUT;
  const int cp = threadIdx.x / FOUT;
  float s = 0.f, q = 0.f;
  for (int r = blockIdx.x * COPIES + cp; r < n; r += gridDim.x * COPIES) {
    float v = h[(size_t)r * FOUT + col];
    s += v;
    q += v * v;
  }
  ls[threadIdx.x] = s;
  lq[threadIdx.x] = q;
  __syncthreads();
  if (threadIdx.x < FOUT) {
    float ts = 0.f, tq = 0.f;
#pragma unroll
    for (int c = 0; c < COPIES; ++c) {
      ts += ls[c * FOUT + col];
      tq += lq[c * FOUT + col];
    }
    unsafeAtomicAdd(&gsum[col], ts);
    unsafeAtomicAdd(&gsq[col], tq);
  }
  __threadfence();
  if (threadIdx.x == 0)
    lastdone = (atomicAdd(ctr, 1) == (int)gridDim.x - 1);
  __syncthreads();
  if (lastdone) {
    if (threadIdx.x < FOUT) {
      int c = threadIdx.x;
      float ts = unsafeAtomicAdd(&gsum[c], 0.f);
      float tq = unsafeAtomicAdd(&gsq[c], 0.f);
      float inv_n = 1.0f / (float)n;
      float mu = ts * inv_n;
      float var = tq * inv_n - mu * mu;
      float sc = g[c] * rsqrtf(var + BN_EPS);
      scale[c] = sc;
      shift[c] = be[c] - mu * sc;
      atomicExch(&gsum[c], 0.f);
      atomicExch(&gsq[c], 0.f);
    }
    if (threadIdx.x == 0) atomicExch(ctr, 0);
  }
}

template <int FOUT, bool RELU>
__global__ void bn_apply_k(const float* __restrict__ in, const float* __restrict__ scale,
                           const float* __restrict__ shift, float* __restrict__ out, int n) {
  constexpr int TPR = FOUT / 4;
  int gid = blockIdx.x * blockDim.x + threadIdx.x;
  int row = gid / TPR, j = gid % TPR;
  if (row >= n) return;
  float4 v = *(const float4*)(in + (size_t)row * FOUT + j * 4);
  float4 sc = *(const float4*)(scale + j * 4);
  float4 sh = *(const float4*)(shift + j * 4);
  float4 o;
  o.x = v.x * sc.x + sh.x;
  o.y = v.y * sc.y + sh.y;
  o.z = v.z * sc.z + sh.z;
  o.w = v.w * sc.w + sh.w;
  if (RELU) {
    o.x = fmaxf(o.x, 0.f);
    o.y = fmaxf(o.y, 0.f);
    o.z = fmaxf(o.z, 0.f);
    o.w = fmaxf(o.w, 0.f);
  }
  *(float4*)(out + (size_t)row * FOUT + j * 4) = o;
}

// ---------------- launch ----------------

static inline size_t pad4(size_t v) { return (v + 3) & ~(size_t)3; }

extern "C" void kernel_launch(void* const* d_in, const int* in_sizes, int n_in,
                              void* d_out, int out_size, void* d_ws, size_t ws_size,
                              hipStream_t stream) {
  const int* x = (const int*)d_in[0];
  const int* ei = (const int*)d_in[1];
  const float* w = (const float*)d_in[2];
  const float* emb = (const float*)d_in[3];
  const float* W1 = (const float*)d_in[4];
  const float* b1 = (const float*)d_in[5];
  const float* g1 = (const float*)d_in[6];
  const float* be1 = (const float*)d_in[7];
  const float* W2 = (const float*)d_in[8];
  const float* b2 = (const float*)d_in[9];
  const float* g2 = (const float*)d_in[10];
  const float* be2 = (const float*)d_in[11];
  const float* W3 = (const float*)d_in[12];
  const float* b3 = (const float*)d_in[13];
  const float* g3 = (const float*)d_in[14];
  const float* be3 = (const float*)d_in[15];

  const int n = in_sizes[0];
  const int e = in_sizes[2];
  const int* src = ei;
  const int* dst = ei + e;

  float* ws = (float*)d_ws;
  size_t off = 0;
  unsigned short* bufA16 = (unsigned short*)(ws + off); off += pad4((size_t)n * 64);  // n*128 bf16
  float* bufB = ws + off; off += pad4((size_t)n * 128);
  unsigned long long* packed = (unsigned long long*)(ws + off); off += pad4((size_t)n * 2);
  float* dinv = ws + off; off += pad4(n);
  int* rowptr = (int*)(ws + off); off += pad4(n + 1);
  int* rank = (int*)(ws + off); off += pad4(e);
  int2* csr = (int2*)(ws + off); off += pad4((size_t)e * 2);
  float* gsum = ws + off; off += 128;
  float* gsq = ws + off; off += 128;
  float* scale = ws + off; off += 128;
  float* shift = ws + off; off += 128;
  int* bsum = (int*)(ws + off); off += 256;
  int* ctr = (int*)(ws + off); off += 4;

  const int B = 256;
  dim3 blk(B);
  const int nb = (n + 255) / 256;  // scan blocks (<=256 required; n=50k -> 196)

  // CSR build (shared by all layers; 1 atomic per edge total)
  zero_graph_k<<<(n + B - 1) / B, blk, 0, stream>>>(packed, gsum, ctr, n);
  hist64_k<<<(e + B - 1) / B, blk, 0, stream>>>(dst, w, packed, rank, e);
  scan_partial_k<<<nb, blk, 0, stream>>>(packed, bsum, dinv, n);
  scan_tops_k<<<1, blk, 0, stream>>>(bsum, rowptr + n, nb);
  scan_final_k<<<nb, blk, 0, stream>>>(packed, bsum, rowptr, n);
  scatter_nb_k<<<(e + B - 1) / B, blk, 0, stream>>>(src, dst, w, rank, dinv, rowptr, csr, e);

  const int gx = (n + 63) / 64;  // RT = 64 for all layers

  // ---- layer 1: gemm(emb[x]) -> bufA16 (bf16); agg -> bufB; stats+finalize
  gemm_tile_k<128, 128, 64, 2, 4, false, true><<<gx, blk, 0, stream>>>(emb, x, nullptr, nullptr, W1, bufA16, n);
  agg_csr_k<128><<<((size_t)n * 16 + B - 1) / B, blk, 0, stream>>>(bufA16, rowptr, csr, dinv, b1, bufB, n);
  bn_stats_fused_k<128><<<256, blk, 0, stream>>>(bufB, gsum, gsq, g1, be1, scale, shift, ctr, n);

  // ---- layer 2
  gemm_tile_k<128, 64, 64, 1, 4, true, false><<<gx, blk, 0, stream>>>(bufB, nullptr, scale, shift, W2, bufA16, n);
  agg_csr_k<64><<<((size_t)n * 8 + B - 1) / B, blk, 0, stream>>>(bufA16, rowptr, csr, dinv, b2, bufB, n);
  bn_stats_fused_k<64><<<256, blk, 0, stream>>>(bufB, gsum, gsq, g2, be2, scale, shift, ctr, n);

  // ---- layer 3
  gemm_tile_k<64, 32, 32, 1, 2, true, false><<<gx, blk, 0, stream>>>(bufB, nullptr, scale, shift, W3, bufA16, n);
  agg_csr_k<32><<<((size_t)n * 4 + B - 1) / B, blk, 0, stream>>>(bufA16, rowptr, csr, dinv, b3, bufB, n);
  bn_stats_fused_k<32><<<256, blk, 0, stream>>>(bufB, gsum, gsq, g3, be3, scale, shift, ctr, n);
  bn_apply_k<32, false><<<((size_t)n * 8 + B - 1) / B, blk, 0, stream>>>(bufB, scale, shift, (float*)d_out, n);
}

// Round 8
// 270.828 us; speedup vs baseline: 7.2724x; 1.1994x over previous
//
#include <hip/hip_runtime.h>
#include <hip/hip_bf16.h>

#define BN_EPS 1e-5f
#define FIXSCALE 16777216.0f            // 2^24
#define FIXINV   5.9604644775390625e-08 // 2^-24
#define LOWMASK  0xFFFFFFFFFFULL        // low 40 bits

typedef __attribute__((ext_vector_type(8))) short bf16x8;
typedef __attribute__((ext_vector_type(4))) float f32x4;

__device__ __forceinline__ unsigned short bfu(float v) {
  return __bfloat16_as_ushort(__float2bfloat16(v));
}
__device__ __forceinline__ unsigned int pk_bf2(float a, float b) {
  return (unsigned int)bfu(a) | ((unsigned int)bfu(b) << 16);
}
__device__ __forceinline__ float bf_lo(unsigned int u) { return __uint_as_float(u << 16); }
__device__ __forceinline__ float bf_hi(unsigned int u) { return __uint_as_float(u & 0xFFFF0000u); }

// ---------------- graph preprocessing (CSR by dst, 1 atomic/edge) ----------------

__global__ void zero_graph_k(unsigned long long* __restrict__ packed,
                             float* __restrict__ gstats, int* __restrict__ ctr, int n) {
  int i = blockIdx.x * blockDim.x + threadIdx.x;
  if (i < n) packed[i] = 0ULL;
  if (i < 256) gstats[i] = 0.f;  // gsum[128] + gsq[128]
  if (i == 0) *ctr = 0;
}

__global__ void hist64_k(const int* __restrict__ dst, const float* __restrict__ w,
                         unsigned long long* __restrict__ packed, int* __restrict__ rank, int e) {
  int i = blockIdx.x * blockDim.x + threadIdx.x;
  if (i < e) {
    unsigned long long fw = (unsigned long long)__float2uint_rn(w[i] * FIXSCALE);
    unsigned long long old = atomicAdd(&packed[dst[i]], (1ULL << 40) | fw);
    rank[i] = (int)(old >> 40);
  }
}

__global__ void scan_partial_k(const unsigned long long* __restrict__ packed,
                               int* __restrict__ bsum, float* __restrict__ dinv, int n) {
  __shared__ int s[256];
  int idx = blockIdx.x * 256 + threadIdx.x;
  unsigned long long p = (idx < n) ? packed[idx] : 0ULL;
  if (idx < n)
    dinv[idx] = rsqrtf(1.0f + (float)((double)(p & LOWMASK) * FIXINV));
  s[threadIdx.x] = (int)(p >> 40);
  __syncthreads();
  for (int off = 128; off > 0; off >>= 1) {
    if (threadIdx.x < off) s[threadIdx.x] += s[threadIdx.x + off];
    __syncthreads();
  }
  if (threadIdx.x == 0) bsum[blockIdx.x] = s[0];
}

__global__ void scan_tops_k(int* __restrict__ bsum, int* __restrict__ total_out, int nb) {
  __shared__ int s[256];
  int t = threadIdx.x;
  int v = (t < nb) ? bsum[t] : 0;
  s[t] = v;
  __syncthreads();
  for (int off = 1; off < 256; off <<= 1) {
    int u = (t >= off) ? s[t - off] : 0;
    __syncthreads();
    s[t] += u;
    __syncthreads();
  }
  if (t < nb) bsum[t] = s[t] - v;  // exclusive
  if (t == 255) *total_out = s[255];
}

__global__ void scan_final_k(const unsigned long long* __restrict__ packed,
                             const int* __restrict__ bsum, int* __restrict__ rowptr, int n) {
  __shared__ int s[256];
  int b = blockIdx.x, t = threadIdx.x;
  int idx = b * 256 + t;
  int v = (idx < n) ? (int)(packed[idx] >> 40) : 0;
  s[t] = v;
  __syncthreads();
  for (int off = 1; off < 256; off <<= 1) {
    int u = (t >= off) ? s[t - off] : 0;
    __syncthreads();
    s[t] += u;
    __syncthreads();
  }
  if (idx < n) rowptr[idx] = bsum[b] + s[t] - v;
}

__global__ void scatter_nb_k(const int* __restrict__ src, const int* __restrict__ dst,
                             const float* __restrict__ w, const int* __restrict__ rank,
                             const float* __restrict__ dinv, const int* __restrict__ rowptr,
                             int2* __restrict__ csr, int e) {
  int i = blockIdx.x * blockDim.x + threadIdx.x;
  if (i < e) {
    int d = dst[i], s = src[i];
    int pos = rowptr[d] + rank[i];
    float c = dinv[s] * w[i] * dinv[d];
    csr[pos] = make_int2(s, __float_as_int(c));
  }
}

// ---------------- weight transpose + bf16 (once per call) ----------------
// wt[c*FIN + k] = bf16(W[k*FOUT + c]) for the three layers, fused.

__global__ void wtrans_k(const float* __restrict__ W1, const float* __restrict__ W2,
                         const float* __restrict__ W3, unsigned short* __restrict__ wt1,
                         unsigned short* __restrict__ wt2, unsigned short* __restrict__ wt3) {
  int idx = blockIdx.x * 256 + threadIdx.x;
  if (idx < 128 * 128) {
    int c = idx >> 7, k = idx & 127;
    wt1[idx] = bfu(W1[k * 128 + c]);
    return;
  }
  idx -= 128 * 128;
  if (idx < 128 * 64) {
    int c = idx >> 7, k = idx & 127;  // wt2: [64][128]
    wt2[idx] = bfu(W2[k * 64 + c]);
    return;
  }
  idx -= 128 * 64;
  if (idx < 64 * 32) {
    int c = idx >> 6, k = idx & 63;   // wt3: [32][64]
    wt3[idx] = bfu(W3[k * 32 + c]);
  }
}

// ---------------- MFMA GEMM: out(bf16)[r][:] = f(H[row]) @ W ----------------
// 64 rows/block, 4 waves x 16 rows, v_mfma_f32_16x16x32_bf16.
// A frag: row=l&15, k=(l>>4)*8+i ; B frag: col=l&15, k=(l>>4)*8+i ;
// C/D: col=l&15, row=(l>>4)*4+reg  [guide §3, m89-verified].

template <int FIN, int FOUT, bool BNIN, bool GATHER>
__global__ __launch_bounds__(256) void gemm_mfma_k(
    const float* __restrict__ H, const int* __restrict__ xidx,
    const float* __restrict__ scale, const float* __restrict__ shift,
    const unsigned short* __restrict__ WtG, unsigned short* __restrict__ out, int n) {
  constexpr int C4 = FIN / 4;
  constexpr int ldH = FIN + 8;   // shorts; +8 pad -> 2-way-max bank aliasing
  constexpr int ldW = FIN + 8;
  constexpr int ldC = FOUT + 4;  // floats
  constexpr int NCT = FOUT / 16;
  constexpr int NK = FIN / 32;
  constexpr int HT_SH = 64 * ldH;
  constexpr int WT_SH = FOUT * ldW;
  constexpr int STAGE_B = (HT_SH + WT_SH) * 2;
  constexpr int C_B = 64 * ldC * 4;
  constexpr int BYTES = STAGE_B > C_B ? STAGE_B : C_B;

  __shared__ __align__(16) char smem[BYTES];
  unsigned short* Ht = (unsigned short*)smem;
  unsigned short* Wt = (unsigned short*)smem + HT_SH;
  float* Cs = (float*)smem;

  const int t = threadIdx.x;
  const int r0 = blockIdx.x * 64;

  // ---- stage H: f32 -> bf16 (+BN/ReLU, +gather), coalesced
  constexpr int NH = 64 * C4 / 256;
#pragma unroll
  for (int i = 0; i < NH; ++i) {
    int idx = t + 256 * i;
    int r = idx / C4, c4 = idx % C4;
    int gr = r0 + r;
    if (gr < n) {
      int srow = GATHER ? xidx[gr] : gr;
      float4 v = *(const float4*)(H + (size_t)srow * FIN + c4 * 4);
      if (BNIN) {
        float4 sc = *(const float4*)(scale + c4 * 4);
        float4 sh = *(const float4*)(shift + c4 * 4);
        v.x = fmaxf(v.x * sc.x + sh.x, 0.f);
        v.y = fmaxf(v.y * sc.y + sh.y, 0.f);
        v.z = fmaxf(v.z * sc.z + sh.z, 0.f);
        v.w = fmaxf(v.w * sc.w + sh.w, 0.f);
      }
      ushort4 p;
      p.x = bfu(v.x); p.y = bfu(v.y); p.z = bfu(v.z); p.w = bfu(v.w);
      *(ushort4*)&Ht[r * ldH + c4 * 4] = p;
    }
  }
  // ---- stage Wt (bf16 global -> padded LDS), coalesced b128
  constexpr int NWU = FOUT * FIN / 8 / 256;
#pragma unroll
  for (int i = 0; i < NWU; ++i) {
    int idx = t + 256 * i;
    int wr = idx / (FIN / 8), w8 = idx % (FIN / 8);
    *(uint4*)&Wt[wr * ldW + w8 * 8] = *(const uint4*)&WtG[wr * FIN + w8 * 8];
  }
  __syncthreads();

  const int w = t >> 6;
  const int l = t & 63;
  const int l15 = l & 15;
  const int kg = l >> 4;
  const int arow = w * 16 + l15;

  f32x4 acc[NCT];
#pragma unroll
  for (int c = 0; c < NCT; ++c) acc[c] = (f32x4){0.f, 0.f, 0.f, 0.f};

#pragma unroll
  for (int kk = 0; kk < NK; ++kk) {
    bf16x8 a = *(const bf16x8*)&Ht[arow * ldH + kk * 32 + kg * 8];
#pragma unroll
    for (int c = 0; c < NCT; ++c) {
      bf16x8 b = *(const bf16x8*)&Wt[(c * 16 + l15) * ldW + kk * 32 + kg * 8];
      acc[c] = __builtin_amdgcn_mfma_f32_16x16x32_bf16(a, b, acc[c], 0, 0, 0);
    }
  }
  __syncthreads();  // done reading Ht/Wt; Cs overlays them

  // ---- C fragments -> LDS (row-major f32)
#pragma unroll
  for (int c = 0; c < NCT; ++c)
#pragma unroll
    for (int m = 0; m < 4; ++m)
      Cs[(w * 16 + kg * 4 + m) * ldC + c * 16 + l15] = acc[c][m];
  __syncthreads();

  // ---- pack bf16 + coalesced store
  constexpr int NU = 64 * FOUT / 8 / 256;
#pragma unroll
  for (int i = 0; i < NU; ++i) {
    int u = t + 256 * i;
    int r = u / (FOUT / 8), c8 = u % (FOUT / 8);
    int gr = r0 + r;
    if (gr < n) {
      const float* p = &Cs[r * ldC + c8 * 8];
      float4 v0 = *(const float4*)p;
      float4 v1 = *(const float4*)(p + 4);
      uint4 o;
      o.x = pk_bf2(v0.x, v0.y); o.y = pk_bf2(v0.z, v0.w);
      o.z = pk_bf2(v1.x, v1.y); o.w = pk_bf2(v1.z, v1.w);
      *(uint4*)&out[(size_t)gr * FOUT + c8 * 8] = o;
    }
  }
}

// ---------------- CSR aggregation (bf16 gather, f32 accumulate) ----------------

template <int FOUT>
__global__ void agg_csr_k(const unsigned short* __restrict__ hW, const int* __restrict__ rowptr,
                          const int2* __restrict__ csr, const float* __restrict__ dinv,
                          const float* __restrict__ b, float* __restrict__ agg, int n) {
  constexpr int TPR = FOUT / 8;
  int gid = blockIdx.x * blockDim.x + threadIdx.x;
  int row = gid / TPR, j = gid % TPR;
  if (row >= n) return;

  const float di = dinv[row];
  const float c0 = di * di;
  const uint4 hu = *(const uint4*)(hW + (size_t)row * FOUT + j * 8);
  const float4 bb0 = *(const float4*)(b + j * 8);
  const float4 bb1 = *(const float4*)(b + j * 8 + 4);
  float4 a0 = make_float4(bf_lo(hu.x) * c0 + bb0.x, bf_hi(hu.x) * c0 + bb0.y,
                          bf_lo(hu.y) * c0 + bb0.z, bf_hi(hu.y) * c0 + bb0.w);
  float4 a1 = make_float4(bf_lo(hu.z) * c0 + bb1.x, bf_hi(hu.z) * c0 + bb1.y,
                          bf_lo(hu.w) * c0 + bb1.z, bf_hi(hu.w) * c0 + bb1.w);

  const int e0 = rowptr[row], e1 = rowptr[row + 1];
  int ee = e0;
  for (; ee + 1 < e1; ee += 2) {
    const int2 ed0 = csr[ee];
    const int2 ed1 = csr[ee + 1];
    const float cc0 = __int_as_float(ed0.y);
    const float cc1 = __int_as_float(ed1.y);
    const uint4 u0 = *(const uint4*)(hW + (size_t)ed0.x * FOUT + j * 8);
    const uint4 u1 = *(const uint4*)(hW + (size_t)ed1.x * FOUT + j * 8);
    a0.x += bf_lo(u0.x) * cc0; a0.y += bf_hi(u0.x) * cc0;
    a0.z += bf_lo(u0.y) * cc0; a0.w += bf_hi(u0.y) * cc0;
    a1.x += bf_lo(u0.z) * cc0; a1.y += bf_hi(u0.z) * cc0;
    a1.z += bf_lo(u0.w) * cc0; a1.w += bf_hi(u0.w) * cc0;
    a0.x += bf_lo(u1.x) * cc1; a0.y += bf_hi(u1.x) * cc1;
    a0.z += bf_lo(u1.y) * cc1; a0.w += bf_hi(u1.y) * cc1;
    a1.x += bf_lo(u1.z) * cc1; a1.y += bf_hi(u1.z) * cc1;
    a1.z += bf_lo(u1.w) * cc1; a1.w += bf_hi(u1.w) * cc1;
  }
  if (ee < e1) {
    const int2 ed0 = csr[ee];
    const float cc0 = __int_as_float(ed0.y);
    const uint4 u0 = *(const uint4*)(hW + (size_t)ed0.x * FOUT + j * 8);
    a0.x += bf_lo(u0.x) * cc0; a0.y += bf_hi(u0.x) * cc0;
    a0.z += bf_lo(u0.y) * cc0; a0.w += bf_hi(u0.y) * cc0;
    a1.x += bf_lo(u0.z) * cc0; a1.y += bf_hi(u0.z) * cc0;
    a1.z += bf_lo(u0.w) * cc0; a1.w += bf_hi(u0.w) * cc0;
  }

  float* orow = agg + (size_t)row * FOUT + j * 8;
  *(float4*)(orow) = a0;
  *(float4*)(orow + 4) = a1;
}

// ---------------- batch norm: stats + finalize fused (last-block-done) ----------------

template <int FOUT>
__global__ void bn_stats_fused_k(const float* __restrict__ h, float* __restrict__ gsum,
                                 float* __restrict__ gsq, const float* __restrict__ g,
                                 const float* __restrict__ be, float* __restrict__ scale,
                                 float* __restrict__ shift, int* __restrict__ ctr, int n) {
  constexpr int COPIES = 256 / FOUT;
  __shared__ float ls[256];
  __shared__ float lq[256];
  __shared__ int lastdone;
  const int col = threadIdx.x % FOUT;
  const int cp = threadIdx.x / FOUT;
  float s = 0.f, q = 0.f;
  for (int r = blockIdx.x * COPIES + cp; r < n; r += gridDim.x * COPIES) {
    float v = h[(size_t)r * FOUT + col];
    s += v;
    q += v * v;
  }
  ls[threadIdx.x] = s;
  lq[threadIdx.x] = q;
  __syncthreads();
  if (threadIdx.x < FOUT) {
    float ts = 0.f, tq = 0.f;
#pragma unroll
    for (int c = 0; c < COPIES; ++c) {
      ts += ls[c * FOUT + col];
      tq += lq[c * FOUT + col];
    }
    unsafeAtomicAdd(&gsum[col], ts);
    unsafeAtomicAdd(&gsq[col], tq);
  }
  __threadfence();
  if (threadIdx.x == 0)
    lastdone = (atomicAdd(ctr, 1) == (int)gridDim.x - 1);
  __syncthreads();
  if (lastdone) {
    if (threadIdx.x < FOUT) {
      int c = threadIdx.x;
      float ts = unsafeAtomicAdd(&gsum[c], 0.f);
      float tq = unsafeAtomicAdd(&gsq[c], 0.f);
      float inv_n = 1.0f / (float)n;
      float mu = ts * inv_n;
      float var = tq * inv_n - mu * mu;
      float sc = g[c] * rsqrtf(var + BN_EPS);
      scale[c] = sc;
      shift[c] = be[c] - mu * sc;
      atomicExch(&gsum[c], 0.f);
      atomicExch(&gsq[c], 0.f);
    }
    if (threadIdx.x == 0) atomicExch(ctr, 0);
  }
}

template <int FOUT, bool RELU>
__global__ void bn_apply_k(const float* __restrict__ in, const float* __restrict__ scale,
                           const float* __restrict__ shift, float* __restrict__ out, int n) {
  constexpr int TPR = FOUT / 4;
  int gid = blockIdx.x * blockDim.x + threadIdx.x;
  int row = gid / TPR, j = gid % TPR;
  if (row >= n) return;
  float4 v = *(const float4*)(in + (size_t)row * FOUT + j * 4);
  float4 sc = *(const float4*)(scale + j * 4);
  float4 sh = *(const float4*)(shift + j * 4);
  float4 o;
  o.x = v.x * sc.x + sh.x;
  o.y = v.y * sc.y + sh.y;
  o.z = v.z * sc.z + sh.z;
  o.w = v.w * sc.w + sh.w;
  if (RELU) {
    o.x = fmaxf(o.x, 0.f);
    o.y = fmaxf(o.y, 0.f);
    o.z = fmaxf(o.z, 0.f);
    o.w = fmaxf(o.w, 0.f);
  }
  *(float4*)(out + (size_t)row * FOUT + j * 4) = o;
}

// ---------------- launch ----------------

static inline size_t pad4(size_t v) { return (v + 3) & ~(size_t)3; }

extern "C" void kernel_launch(void* const* d_in, const int* in_sizes, int n_in,
                              void* d_out, int out_size, void* d_ws, size_t ws_size,
                              hipStream_t stream) {
  const int* x = (const int*)d_in[0];
  const int* ei = (const int*)d_in[1];
  const float* w = (const float*)d_in[2];
  const float* emb = (const float*)d_in[3];
  const float* W1 = (const float*)d_in[4];
  const float* b1 = (const float*)d_in[5];
  const float* g1 = (const float*)d_in[6];
  const float* be1 = (const float*)d_in[7];
  const float* W2 = (const float*)d_in[8];
  const float* b2 = (const float*)d_in[9];
  const float* g2 = (const float*)d_in[10];
  const float* be2 = (const float*)d_in[11];
  const float* W3 = (const float*)d_in[12];
  const float* b3 = (const float*)d_in[13];
  const float* g3 = (const float*)d_in[14];
  const float* be3 = (const float*)d_in[15];

  const int n = in_sizes[0];
  const int e = in_sizes[2];
  const int* src = ei;
  const int* dst = ei + e;

  float* ws = (float*)d_ws;
  size_t off = 0;
  unsigned short* bufA16 = (unsigned short*)(ws + off); off += pad4((size_t)n * 64);  // n*128 bf16
  float* bufB = ws + off; off += pad4((size_t)n * 128);
  unsigned long long* packed = (unsigned long long*)(ws + off); off += pad4((size_t)n * 2);
  float* dinv = ws + off; off += pad4(n);
  int* rowptr = (int*)(ws + off); off += pad4(n + 1);
  int* rank = (int*)(ws + off); off += pad4(e);
  int2* csr = (int2*)(ws + off); off += pad4((size_t)e * 2);
  unsigned short* wt1 = (unsigned short*)(ws + off); off += 128 * 128 / 2;
  unsigned short* wt2 = (unsigned short*)(ws + off); off += 128 * 64 / 2;
  unsigned short* wt3 = (unsigned short*)(ws + off); off += 64 * 32 / 2;
  float* gsum = ws + off; off += 128;
  float* gsq = ws + off; off += 128;
  float* scale = ws + off; off += 128;
  float* shift = ws + off; off += 128;
  int* bsum = (int*)(ws + off); off += 256;
  int* ctr = (int*)(ws + off); off += 4;

  const int B = 256;
  dim3 blk(B);
  const int nb = (n + 255) / 256;  // scan blocks (<=256 required; n=50k -> 196)

  // weight transpose + bf16 (tiny, once per call)
  wtrans_k<<<(128 * 128 + 128 * 64 + 64 * 32 + B - 1) / B, blk, 0, stream>>>(W1, W2, W3, wt1, wt2, wt3);

  // CSR build (shared by all layers; 1 atomic per edge total)
  zero_graph_k<<<(n + B - 1) / B, blk, 0, stream>>>(packed, gsum, ctr, n);
  hist64_k<<<(e + B - 1) / B, blk, 0, stream>>>(dst, w, packed, rank, e);
  scan_partial_k<<<nb, blk, 0, stream>>>(packed, bsum, dinv, n);
  scan_tops_k<<<1, blk, 0, stream>>>(bsum, rowptr + n, nb);
  scan_final_k<<<nb, blk, 0, stream>>>(packed, bsum, rowptr, n);
  scatter_nb_k<<<(e + B - 1) / B, blk, 0, stream>>>(src, dst, w, rank, dinv, rowptr, csr, e);

  const int gx = (n + 63) / 64;  // 64 rows per gemm block

  // ---- layer 1: mfma-gemm(emb[x]) -> bufA16; agg -> bufB; stats+finalize
  gemm_mfma_k<128, 128, false, true><<<gx, blk, 0, stream>>>(emb, x, nullptr, nullptr, wt1, bufA16, n);
  agg_csr_k<128><<<((size_t)n * 16 + B - 1) / B, blk, 0, stream>>>(bufA16, rowptr, csr, dinv, b1, bufB, n);
  bn_stats_fused_k<128><<<256, blk, 0, stream>>>(bufB, gsum, gsq, g1, be1, scale, shift, ctr, n);

  // ---- layer 2
  gemm_mfma_k<128, 64, true, false><<<gx, blk, 0, stream>>>(bufB, nullptr, scale, shift, wt2, bufA16, n);
  agg_csr_k<64><<<((size_t)n * 8 + B - 1) / B, blk, 0, stream>>>(bufA16, rowptr, csr, dinv, b2, bufB, n);
  bn_stats_fused_k<64><<<256, blk, 0, stream>>>(bufB, gsum, gsq, g2, be2, scale, shift, ctr, n);

  // ---- layer 3
  gemm_mfma_k<64, 32, true, false><<<gx, blk, 0, stream>>>(bufB, nullptr, scale, shift, wt3, bufA16, n);
  agg_csr_k<32><<<((size_t)n * 4 + B - 1) / B, blk, 0, stream>>>(bufA16, rowptr, csr, dinv, b3, bufB, n);
  bn_stats_fused_k<32><<<256, blk, 0, stream>>>(bufB, gsum, gsq, g3, be3, scale, shift, ctr, n);
  bn_apply_k<32, false><<<((size_t)n * 8 + B - 1) / B, blk, 0, stream>>>(bufB, scale, shift, (float*)d_out, n);
}